// Round 2
// baseline (4891.165 us; speedup 1.0000x reference)
//
#include <hip/hip_runtime.h>
#include <hip/hip_bf16.h>
#include <cstdint>
#include <cstddef>

#define VOCABN 10000
#define FEATC 512
#define EMBN 256
#define HIDN 512
#define AFFN 512
#define BB 32
#define TTN 60
#define PPN 196
#define XKN 1280   // x layout per batch: emb[0,256) | ctx[256,768) | h[768,1280)

using bf16 = __hip_bfloat16;

typedef __attribute__((ext_vector_type(8))) short short8;
typedef __attribute__((ext_vector_type(4))) float f32x4;

__device__ __forceinline__ float b2f(bf16 x){ return __bfloat162float(x); }
__device__ __forceinline__ float fexp2(float x){ return __builtin_amdgcn_exp2f(x); }
__device__ __forceinline__ float frcp(float x){ return __builtin_amdgcn_rcpf(x); }
__device__ __forceinline__ float fsig(float x){ return frcp(1.f + fexp2(-1.4426950408889634f*x)); }
__device__ __forceinline__ float ftanhf(float x){ return 1.f - 2.f*frcp(1.f + fexp2(2.8853900817779268f*x)); }

__device__ __forceinline__ void unpack8(uint4 u, float* f){
  f[0] = __uint_as_float(u.x << 16); f[1] = __uint_as_float(u.x & 0xffff0000u);
  f[2] = __uint_as_float(u.y << 16); f[3] = __uint_as_float(u.y & 0xffff0000u);
  f[4] = __uint_as_float(u.z << 16); f[5] = __uint_as_float(u.z & 0xffff0000u);
  f[6] = __uint_as_float(u.w << 16); f[7] = __uint_as_float(u.w & 0xffff0000u);
}

// ---------- dtype probe (also zeroes the grid-barrier counter) ----------
__global__ void __launch_bounds__(256) k_probe(const uint32_t* __restrict__ w, int* __restrict__ flag,
                                               unsigned* __restrict__ bar){
  __shared__ int s;
  if (threadIdx.x == 0) s = 0;
  __syncthreads();
  int hit = 0;
  for (int i = threadIdx.x; i < 32768; i += 256){
    uint32_t v = w[i];
    if (((v & 0x7F800000u) == 0x7F800000u) || ((v & 0x00007F80u) == 0x00007F80u)) hit = 1;
  }
  if (hit) atomicOr(&s, 1);
  __syncthreads();
  if (threadIdx.x == 0){ flag[0] = s; bar[0] = 0u; }
}

// ---------- canonicalize one tensor to bf16 ----------
__global__ void __launch_bounds__(256) k_cvt(const void* __restrict__ src, bf16* __restrict__ dst,
                                             int nquad, const int* __restrict__ flag){
  bool f32 = flag[0] != 0;
  int stride = gridDim.x * 256;
  for (int i = blockIdx.x*256 + threadIdx.x; i < nquad; i += stride){
    if (f32){
      float4 v = reinterpret_cast<const float4*>(src)[i];
      bf16* d = dst + 4*(size_t)i;
      d[0] = __float2bfloat16(v.x); d[1] = __float2bfloat16(v.y);
      d[2] = __float2bfloat16(v.z); d[3] = __float2bfloat16(v.w);
    } else {
      reinterpret_cast<uint2*>(dst)[i] = reinterpret_cast<const uint2*>(src)[i];
    }
  }
}

// ---------- feats[b][p][c] = cnn[b][c][p] ----------
__global__ void __launch_bounds__(256) k_transpose(const bf16* __restrict__ cnn, bf16* __restrict__ feats){
  __shared__ bf16 tile[32][34];
  int ct = blockIdx.x, pt = blockIdx.y, b = blockIdx.z;
  int tid = threadIdx.x;
  int lc = tid >> 5, lp = tid & 31;
  int p = pt*32 + lp;
  #pragma unroll
  for (int i=0;i<4;i++){
    int cc = ct*32 + lc + i*8;
    bf16 v = __float2bfloat16(0.f);
    if (p < PPN) v = cnn[((size_t)b*FEATC + cc)*PPN + p];
    tile[lc + i*8][lp] = v;
  }
  __syncthreads();
  #pragma unroll
  for (int i=0;i<4;i++){
    int pp = pt*32 + lc + i*8;
    if (pp < PPN) feats[((size_t)b*PPN + pp)*FEATC + ct*32 + lp] = tile[lp][lc + i*8];
  }
}

// ---------- WkT = Wk^T (512x512 bf16) ----------
__global__ void __launch_bounds__(256) k_wkt(const bf16* __restrict__ W, bf16* __restrict__ WT){
  __shared__ bf16 tile[32][33];
  const int c0 = blockIdx.x*32, r0 = blockIdx.y*32;
  const int lc = threadIdx.x >> 5, lp = threadIdx.x & 31;
  #pragma unroll
  for (int i=0;i<4;i++) tile[lc + i*8][lp] = W[(size_t)(r0 + lc + i*8)*HIDN + c0 + lp];
  __syncthreads();
  #pragma unroll
  for (int i=0;i<4;i++) WT[(size_t)(c0 + lc + i*8)*HIDN + r0 + lp] = tile[lp][lc + i*8];
}

// ---------- Wcat[r'][0..1280) : r' = j*4+gate, row = [Wih(g*512+j) | Whh(g*512+j)] ----------
__global__ void __launch_bounds__(256) k_wcat(const bf16* __restrict__ Wih, const bf16* __restrict__ Whh,
      const bf16* __restrict__ bih, const bf16* __restrict__ bhh,
      bf16* __restrict__ Wcat, float* __restrict__ biasCat){
  const int rloc = threadIdx.x >> 5, lane32 = threadIdx.x & 31;
  const int r = blockIdx.x*8 + rloc;
  const int j = r >> 2, g = r & 3;
  const int src = g*HIDN + j;
  for (int e4 = lane32; e4 < 320; e4 += 32){
    const int e = e4*4;
    uint2 v = (e < 768) ? *reinterpret_cast<const uint2*>(Wih + (size_t)src*768 + e)
                        : *reinterpret_cast<const uint2*>(Whh + (size_t)src*HIDN + (e - 768));
    *reinterpret_cast<uint2*>(Wcat + (size_t)r*XKN + e) = v;
  }
  if (lane32 == 0) biasCat[r] = b2f(bih[src]) + b2f(bhh[src]);
}

// ---------- g = mean_p cnn ; h0 = g@Wh^T+bh ; c0 = g@Wc^T+bc ----------
__global__ void __launch_bounds__(256) k_init(const bf16* __restrict__ cnn,
      const bf16* __restrict__ Wh, const bf16* __restrict__ bh,
      const bf16* __restrict__ Wc, const bf16* __restrict__ bc,
      float* __restrict__ h, float* __restrict__ c){
  __shared__ float gl[FEATC];
  int b = blockIdx.x, tid = threadIdx.x;
  for (int cc = tid; cc < FEATC; cc += 256){
    const bf16* src = cnn + ((size_t)b*FEATC + cc)*PPN;
    const uint2* sp = reinterpret_cast<const uint2*>(src);
    float acc = 0.f;
    for (int q=0;q<PPN/4;q++){
      uint2 u = sp[q];
      acc += __uint_as_float(u.x<<16) + __uint_as_float(u.x&0xffff0000u)
           + __uint_as_float(u.y<<16) + __uint_as_float(u.y&0xffff0000u);
    }
    gl[cc] = acc * (1.0f/196.0f);
  }
  __syncthreads();
  for (int i = tid; i < HIDN; i += 256){
    const uint4* wr1 = reinterpret_cast<const uint4*>(Wh + (size_t)i*FEATC);
    const uint4* wr2 = reinterpret_cast<const uint4*>(Wc + (size_t)i*FEATC);
    float a1 = 0.f, a2 = 0.f;
    #pragma unroll 4
    for (int k8=0; k8<FEATC/8; k8++){
      float w1[8], w2[8];
      unpack8(wr1[k8], w1); unpack8(wr2[k8], w2);
      const float* gp = &gl[k8*8];
      #pragma unroll
      for (int j=0;j<8;j++){ a1 = fmaf(w1[j], gp[j], a1); a2 = fmaf(w2[j], gp[j], a2); }
    }
    h[b*HIDN+i] = a1 + b2f(bh[i]);
    c[b*HIDN+i] = a2 + b2f(bc[i]);
  }
}

// ---------- initial hk partials from h0 ----------
__global__ void __launch_bounds__(512) k_hk0(const bf16* __restrict__ WkT,
      const float* __restrict__ h, float* __restrict__ part){
  __shared__ float hl[64];
  const int tid = threadIdx.x;
  const int k = blockIdx.x & 7, b = blockIdx.x >> 3;
  if (tid < 64) hl[tid] = h[b*HIDN + k*64 + tid];
  __syncthreads();
  const bf16* wp = WkT + (size_t)(k*64)*AFFN + tid;
  float acc = 0.f;
  #pragma unroll 8
  for (int j=0; j<64; j++) acc = fmaf(b2f(wp[(size_t)j*AFFN]), hl[j], acc);
  part[((size_t)(b*8 + k))*AFFN + tid] = acc;
}

// ---------- generic MFMA GEMM: C[M][N] = A[M][K] @ Bw[N][K]^T (+bias) ----------
// OUTMODE 0: f32 out. 1: dtype by flag (1->f32, 0->bf16). 2: always bf16.
// NT: nontemporal C stores (for large streaming outputs).
template<int OUTMODE, bool BIAS, bool NT>
__global__ void __launch_bounds__(256) gemm_bt(const bf16* __restrict__ A, const bf16* __restrict__ Bw,
        const bf16* __restrict__ bias, void* __restrict__ Cout, int M, int N, int K,
        const int* __restrict__ flag){
  __shared__ __align__(16) bf16 As[64][40];
  __shared__ __align__(16) bf16 Bs[64][40];
  int tid = threadIdx.x;
  int m0 = blockIdx.y*64, n0 = blockIdx.x*64;
  int lr = tid >> 2;
  int lk = (tid & 3)*8;
  int wave = tid >> 6, lane = tid & 63;
  int ml = lane & 15, kg = lane >> 4;
  f32x4 acc0 = {0.f,0.f,0.f,0.f}, acc1 = acc0, acc2 = acc0, acc3 = acc0;
  for (int k0=0; k0<K; k0+=32){
    __syncthreads();
    {
      uint4 av = *reinterpret_cast<const uint4*>(A + (size_t)(m0+lr)*K + k0 + lk);
      *reinterpret_cast<uint4*>(&As[lr][lk]) = av;
      uint4 bv = make_uint4(0u,0u,0u,0u);
      int bn = n0 + lr;
      if (bn < N) bv = *reinterpret_cast<const uint4*>(Bw + (size_t)bn*K + k0 + lk);
      *reinterpret_cast<uint4*>(&Bs[lr][lk]) = bv;
    }
    __syncthreads();
    short8 af = *reinterpret_cast<const short8*>(&As[wave*16 + ml][kg*8]);
    short8 b0 = *reinterpret_cast<const short8*>(&Bs[ 0 + ml][kg*8]);
    short8 b1 = *reinterpret_cast<const short8*>(&Bs[16 + ml][kg*8]);
    short8 b2 = *reinterpret_cast<const short8*>(&Bs[32 + ml][kg*8]);
    short8 b3 = *reinterpret_cast<const short8*>(&Bs[48 + ml][kg*8]);
    acc0 = __builtin_amdgcn_mfma_f32_16x16x32_bf16(af, b0, acc0, 0,0,0);
    acc1 = __builtin_amdgcn_mfma_f32_16x16x32_bf16(af, b1, acc1, 0,0,0);
    acc2 = __builtin_amdgcn_mfma_f32_16x16x32_bf16(af, b2, acc2, 0,0,0);
    acc3 = __builtin_amdgcn_mfma_f32_16x16x32_bf16(af, b3, acc3, 0,0,0);
  }
  bool of32;
  if (OUTMODE == 0) of32 = true;
  else if (OUTMODE == 2) of32 = false;
  else of32 = (flag[0] != 0);
  int mb = m0 + wave*16 + (lane>>4)*4;
  int cl = lane & 15;
  f32x4 av[4] = {acc0, acc1, acc2, acc3};
  #pragma unroll
  for (int j=0;j<4;j++){
    int n = n0 + j*16 + cl;
    if (n < N){
      float bv = BIAS ? b2f(bias[n]) : 0.f;
      #pragma unroll
      for (int rr=0; rr<4; rr++){
        float v = av[j][rr] + bv;
        if (of32){
          float* p = &((float*)Cout)[(size_t)(mb+rr)*N + n];
          if (NT) __builtin_nontemporal_store(v, p); else *p = v;
        } else {
          bf16 hv = __float2bfloat16(v);
          short sv = *reinterpret_cast<short*>(&hv);
          short* p = reinterpret_cast<short*>(&((bf16*)Cout)[(size_t)(mb+rr)*N + n]);
          if (NT) __builtin_nontemporal_store(sv, p); else *p = sv;
        }
      }
    }
  }
}

// ---------- grid barrier (monotonic counter, agent scope) ----------
__device__ __forceinline__ void gbar(unsigned* bar, unsigned target){
  __syncthreads();
  if (threadIdx.x == 0){
    __threadfence();   // release: drain + writeback so other XCDs see our stores
    __hip_atomic_fetch_add(bar, 1u, __ATOMIC_RELEASE, __HIP_MEMORY_SCOPE_AGENT);
    unsigned guard = 0;
    while (__hip_atomic_load(bar, __ATOMIC_ACQUIRE, __HIP_MEMORY_SCOPE_AGENT) < target){
      __builtin_amdgcn_s_sleep(2);
      if (++guard > 100000000u) break;   // fail visibly rather than hang forever
    }
    __threadfence();   // acquire: invalidate L1/L2 so we read fresh remote data
  }
  __syncthreads();
}

// ---------- persistent recurrence kernel ----------
// 256 blocks x 512 threads, 1 block/CU. block (b,k): b = bid>>3, k = bid&7.
// Block owns: p-slice [p0,p0+np) of kv/feats (LDS-resident all 60 steps),
//             gate-row slice k*256..k*256+256 of Wcat, h/c slice j in [k*64,(k+1)*64).
// Per step: 2 grid barriers. c-state lives in registers.
__global__ void __launch_bounds__(512) k_pers(
    const bf16* __restrict__ kvB, const bf16* __restrict__ feats,
    const bf16* __restrict__ WkT, const bf16* __restrict__ Wcat,
    const float* __restrict__ biasCat, const bf16* __restrict__ wa,
    const bf16* __restrict__ table, const int* __restrict__ captions,
    float* __restrict__ hstate,          // [2][32][512] parity dbuf
    const float* __restrict__ cinit,     // [32][512]
    float* __restrict__ part,            // [32][8][512]
    float* __restrict__ Vpart,           // [32][8][512]
    float* __restrict__ mS,              // [32][8][2]
    bf16* __restrict__ Hb, unsigned* __restrict__ bar)
{
  __shared__ __align__(16) bf16 kv_s[25][512];
  __shared__ __align__(16) bf16 ft_s[25][512];
  __shared__ __align__(16) float xs[XKN];
  __shared__ __align__(16) float hks[AFFN];
  __shared__ float gs[256];
  __shared__ float zes[32];
  __shared__ float es[32];
  __shared__ float hnew[64];

  const int tid = threadIdx.x;
  const int bid = blockIdx.x;
  const int k = bid & 7, b = bid >> 3;
  const int np = (k < 4) ? 25 : 24;
  const int p0 = (k < 4) ? k*25 : 100 + (k-4)*24;
  const int lane = tid & 63, wv = tid >> 6;

  // ---- prologue: stage kv/feats p-slice into LDS (once, reused 60 steps) ----
  {
    const uint4* kvg = reinterpret_cast<const uint4*>(kvB + ((size_t)(b*PPN + p0))*AFFN);
    const uint4* ftg = reinterpret_cast<const uint4*>(feats + ((size_t)(b*PPN + p0))*FEATC);
    uint4* kvl = reinterpret_cast<uint4*>(&kv_s[0][0]);
    uint4* ftl = reinterpret_cast<uint4*>(&ft_s[0][0]);
    const int nq = np*64;
    for (int i = tid; i < nq; i += 512){ kvl[i] = kvg[i]; ftl[i] = ftg[i]; }
  }
  float creg = 0.f;
  if (tid < 64) creg = cinit[b*HIDN + k*64 + tid];
  float wf[8];
  unpack8(*reinterpret_cast<const uint4*>(wa + lane*8), wf);
  __syncthreads();

  unsigned bexp = 0;
  for (int t = 0; t < TTN; t++){
    // ================= Phase A =================
    // hk[a] = sum of 8 partials (written last step phase B, across barrier B)
    {
      const float* pp = part + (size_t)b*8*AFFN + tid;
      float s = pp[0];
      #pragma unroll
      for (int kk=1; kk<8; kk++) s += pp[(size_t)kk*AFFN];
      hks[tid] = s;
    }
    if (tid < EMBN){
      const int tok = captions[b*TTN + t];
      xs[tid] = b2f(table[(size_t)tok*EMBN + tid]);
    }
    __syncthreads();

    // z for my p-slice (wave per p), kv from LDS
    {
      float hf[8];
      const float4* hp = reinterpret_cast<const float4*>(&hks[lane*8]);
      float4 t0 = hp[0], t1 = hp[1];
      hf[0]=t0.x; hf[1]=t0.y; hf[2]=t0.z; hf[3]=t0.w;
      hf[4]=t1.x; hf[5]=t1.y; hf[6]=t1.z; hf[7]=t1.w;
      for (int pl = wv; pl < np; pl += 8){
        float kf[8]; unpack8(*reinterpret_cast<const uint4*>(&kv_s[pl][lane*8]), kf);
        float acc = wf[0]*ftanhf(kf[0]+hf[0]) + wf[1]*ftanhf(kf[1]+hf[1])
                  + wf[2]*ftanhf(kf[2]+hf[2]) + wf[3]*ftanhf(kf[3]+hf[3])
                  + wf[4]*ftanhf(kf[4]+hf[4]) + wf[5]*ftanhf(kf[5]+hf[5])
                  + wf[6]*ftanhf(kf[6]+hf[6]) + wf[7]*ftanhf(kf[7]+hf[7]);
        #pragma unroll
        for (int s=1;s<64;s<<=1) acc += __shfl_xor(acc, s, 64);
        if (lane == 0) zes[pl] = acc;
      }
    }
    __syncthreads();

    // partial softmax over my np z's (wave 0): m_k, S_k, es[]
    if (wv == 0){
      float v = (lane < np) ? zes[lane] : -1e30f;
      float m = v;
      #pragma unroll
      for (int s=1;s<64;s<<=1) m = fmaxf(m, __shfl_xor(m, s, 64));
      float e = (lane < np) ? fexp2((v - m)*1.4426950408889634f) : 0.f;
      float ssum = e;
      #pragma unroll
      for (int s=1;s<64;s<<=1) ssum += __shfl_xor(ssum, s, 64);
      if (lane < np) es[lane] = e;
      if (lane == 0){ mS[(b*8+k)*2 + 0] = m; mS[(b*8+k)*2 + 1] = ssum; }
    }
    __syncthreads();

    // V_k[c] = sum_{p in slice} e_p * feats[p][c]  (feats from LDS)
    {
      float acc = 0.f;
      #pragma unroll 4
      for (int pl=0; pl<np; pl++) acc = fmaf(es[pl], b2f(ft_s[pl][tid]), acc);
      Vpart[((size_t)(b*8+k))*FEATC + tid] = acc;
    }

    bexp += 256; gbar(bar, bexp);   // -------- barrier A --------

    // ================= Phase B =================
    // combine slice partials -> ctx; gather h (parity-old)
    {
      const float* msb = mS + b*16;
      float mk[8], sk[8], m = -1e30f;
      #pragma unroll
      for (int kk=0;kk<8;kk++){ mk[kk] = msb[kk*2]; sk[kk] = msb[kk*2+1]; m = fmaxf(m, mk[kk]); }
      float Z = 0.f, w[8];
      #pragma unroll
      for (int kk=0;kk<8;kk++){ w[kk] = fexp2((mk[kk]-m)*1.4426950408889634f); Z = fmaf(sk[kk], w[kk], Z); }
      const float inv = 1.0f / Z;
      float acc = 0.f;
      const float* vp = Vpart + (size_t)b*8*FEATC + tid;
      #pragma unroll
      for (int kk=0;kk<8;kk++) acc = fmaf(w[kk], vp[(size_t)kk*FEATC], acc);
      xs[EMBN + tid] = acc * inv;
      xs[EMBN + FEATC + tid] = hstate[(size_t)(t&1)*BB*HIDN + b*HIDN + tid];
    }
    __syncthreads();

    // gates: 2 threads per row (k-halves), rows k*256 + r, r = j*4+gate
    {
      const int r = tid >> 1, half = tid & 1;
      const int rowg = k*256 + r;
      const bf16* wrow = Wcat + (size_t)rowg*XKN + half*640;
      const float* xp = xs + half*640;
      float a0=0.f,a1=0.f,a2=0.f,a3=0.f;
      #pragma unroll 4
      for (int e=0; e<640; e+=8){
        float w8[8]; unpack8(*reinterpret_cast<const uint4*>(wrow + e), w8);
        float4 x0 = *reinterpret_cast<const float4*>(xp + e);
        float4 x1 = *reinterpret_cast<const float4*>(xp + e + 4);
        a0 = fmaf(w8[0],x0.x,a0); a1 = fmaf(w8[1],x0.y,a1);
        a2 = fmaf(w8[2],x0.z,a2); a3 = fmaf(w8[3],x0.w,a3);
        a0 = fmaf(w8[4],x1.x,a0); a1 = fmaf(w8[5],x1.y,a1);
        a2 = fmaf(w8[6],x1.z,a2); a3 = fmaf(w8[7],x1.w,a3);
      }
      float acc = (a0+a1)+(a2+a3);
      acc += __shfl_xor(acc, 1, 64);
      if (half == 0) gs[r] = acc + biasCat[rowg];
    }
    __syncthreads();

    // cell update for my 64 j's (c in registers)
    if (tid < 64){
      const int j = k*64 + tid;
      float gi = gs[tid*4+0], gf = gs[tid*4+1], gg = gs[tid*4+2], go = gs[tid*4+3];
      float cn = fsig(gf)*creg + fsig(gi)*ftanhf(gg);
      float hn = fsig(go)*ftanhf(cn);
      creg = cn;
      hstate[(size_t)((t+1)&1)*BB*HIDN + b*HIDN + j] = hn;
      Hb[((size_t)b*TTN + t)*HIDN + j] = __float2bfloat16(hn);
      hnew[tid] = hn;
    }
    __syncthreads();

    // next step's hk partial over my h slice
    {
      const bf16* wp = WkT + (size_t)(k*64)*AFFN + tid;
      float acc = 0.f;
      #pragma unroll 8
      for (int j=0;j<64;j++) acc = fmaf(b2f(wp[(size_t)j*AFFN]), hnew[j], acc);
      part[((size_t)(b*8+k))*AFFN + tid] = acc;
    }

    bexp += 256; gbar(bar, bexp);   // -------- barrier B --------
  }
}

static inline int cvt_grid(int nquad){ int g = (nquad + 255)/256; return g > 1024 ? 1024 : g; }

extern "C" void kernel_launch(void* const* d_in, const int* in_sizes, int n_in,
                              void* d_out, int out_size, void* d_ws, size_t ws_size,
                              hipStream_t stream) {
  const int* captions = (const int*)d_in[1];
  char* ws = (char*)d_ws;

  // ---- workspace layout (bytes) ----
  bf16*  feats  = (bf16*) (ws + 0);           // [6272][512] bf16
  bf16*  kvB    = (bf16*) (ws + 6422528);     // [6272][512] bf16
  float* hstate = (float*)(ws + 12845056);    // [2][32][512] f32
  float* cstate = (float*)(ws + 12976128);    // [32][512] f32
  float* part   = (float*)(ws + 13041664);    // [32][8][512] f32
  float* Vpart  = (float*)(ws + 13565952);    // [32][8][512] f32
  float* mS     = (float*)(ws + 14090240);    // [32][8][2] f32
  unsigned* bar = (unsigned*)(ws + 14092416); // barrier counter (own line)
  bf16*  Hb     = (bf16*) (ws + 14092544);    // [32][60][512] bf16
  bf16*  cnnB   = (bf16*) (ws + 16058624);    // [32][512][196] bf16 (dead after transpose+init)
  bf16*  WcatB  = (bf16*) (ws + 16058624);    // [2048][1280] bf16 — ALIASES cnnB
  bf16*  tableB = (bf16*) (ws + 22481152);
  bf16*  WkB    = (bf16*) (ws + 27601152);
  bf16*  WkTB   = (bf16*) (ws + 28125440);
  bf16*  WvB    = (bf16*) (ws + 28649728);
  bf16*  WhB    = (bf16*) (ws + 29174016);
  bf16*  WcB    = (bf16*) (ws + 29698304);
  bf16*  WihB   = (bf16*) (ws + 30222592);
  bf16*  WhhB   = (bf16*) (ws + 33368320);
  bf16*  WfcB   = (bf16*) (ws + 35465472);
  bf16*  waB    = (bf16*) (ws + 45705472);
  bf16*  bhB    = (bf16*) (ws + 45706496);
  bf16*  bcB    = (bf16*) (ws + 45707520);
  bf16*  bihB   = (bf16*) (ws + 45708544);
  bf16*  bhhB   = (bf16*) (ws + 45712640);
  bf16*  bfcB   = (bf16*) (ws + 45716736);
  float* biasCat= (float*)(ws + 45736736);
  int*   flag   = (int*)  (ws + 45744928);
  if (ws_size < 45744944ull) return;

  // 1) dtype probe + barrier reset
  k_probe<<<1, 256, 0, stream>>>((const uint32_t*)d_in[5], flag, bar);

  // 2) canonicalize to bf16
  struct CvtJob { const void* src; bf16* dst; int n; };
  const CvtJob jobs[15] = {
    {d_in[0],  cnnB,   3211264}, {d_in[2],  WkB,  262144}, {d_in[3],  WvB,  262144},
    {d_in[4],  waB,    512},     {d_in[5],  tableB, 2560000},
    {d_in[6],  WhB,    262144},  {d_in[7],  bhB,  512},
    {d_in[8],  WcB,    262144},  {d_in[9],  bcB,  512},
    {d_in[10], WihB,   1572864}, {d_in[11], WhhB, 1048576},
    {d_in[12], bihB,   2048},    {d_in[13], bhhB, 2048},
    {d_in[14], WfcB,   5120000}, {d_in[15], bfcB, 10000},
  };
  for (int i = 0; i < 15; i++){
    int nq = jobs[i].n / 4;
    k_cvt<<<cvt_grid(nq), 256, 0, stream>>>(jobs[i].src, jobs[i].dst, nq, flag);
  }

  // 3) precompute (cnnB consumers run BEFORE k_wcat overwrites that region)
  k_transpose<<<dim3(16,7,32), 256, 0, stream>>>(cnnB, feats);
  k_init<<<32, 256, 0, stream>>>(cnnB, WhB, bhB, WcB, bcB, hstate, cstate);  // parity 0
  k_wkt<<<dim3(16,16), 256, 0, stream>>>(WkB, WkTB);
  k_wcat<<<256, 256, 0, stream>>>(WihB, WhhB, bihB, bhhB, WcatB, biasCat);
  k_hk0<<<256, 512, 0, stream>>>(WkTB, hstate, part);
  gemm_bt<2,false,false><<<dim3(8,98), 256, 0, stream>>>(feats, WvB, (const bf16*)nullptr,
                                                   (void*)kvB, 6272, 512, 512, (const int*)nullptr);

  // 4) the whole recurrence: ONE persistent kernel, 2 grid barriers per step
  k_pers<<<256, 512, 0, stream>>>(kvB, feats, WkTB, WcatB, biasCat, waB, tableB,
                                  captions, hstate, cstate, part, Vpart, mS, Hb, bar);

  // 5) logits = Hb @ Wfc^T + bfc (nontemporal C stores: don't thrash L2)
  gemm_bt<1,true,true><<<dim3(157,30), 256, 0, stream>>>(Hb, WfcB, bfcB, d_out,
                                                    1920, 10000, 512, flag);
}

// Round 3
// 1939.659 us; speedup vs baseline: 2.5217x; 2.5217x over previous
//
#include <hip/hip_runtime.h>
#include <hip/hip_bf16.h>
#include <cstdint>
#include <cstddef>

#define VOCABN 10000
#define FEATC 512
#define EMBN 256
#define HIDN 512
#define AFFN 512
#define BB 32
#define TTN 60
#define PPN 196
#define XKN 1280   // x layout per batch: emb[0,256) | ctx[256,768) | h[768,1280)

using bf16 = __hip_bfloat16;

typedef __attribute__((ext_vector_type(8))) short short8;
typedef __attribute__((ext_vector_type(4))) float f32x4;

__device__ __forceinline__ float b2f(bf16 x){ return __bfloat162float(x); }
__device__ __forceinline__ float fexp2(float x){ return __builtin_amdgcn_exp2f(x); }
__device__ __forceinline__ float frcp(float x){ return __builtin_amdgcn_rcpf(x); }
__device__ __forceinline__ float fsig(float x){ return frcp(1.f + fexp2(-1.4426950408889634f*x)); }
__device__ __forceinline__ float ftanhf(float x){ return 1.f - 2.f*frcp(1.f + fexp2(2.8853900817779268f*x)); }

// relaxed agent-scope accessors: device-coherent, NO cache-maintenance fences
__device__ __forceinline__ float aload(const float* p){
  return __hip_atomic_load((float*)p, __ATOMIC_RELAXED, __HIP_MEMORY_SCOPE_AGENT);
}
__device__ __forceinline__ void astore(float* p, float v){
  __hip_atomic_store(p, v, __ATOMIC_RELAXED, __HIP_MEMORY_SCOPE_AGENT);
}

__device__ __forceinline__ void unpack8(uint4 u, float* f){
  f[0] = __uint_as_float(u.x << 16); f[1] = __uint_as_float(u.x & 0xffff0000u);
  f[2] = __uint_as_float(u.y << 16); f[3] = __uint_as_float(u.y & 0xffff0000u);
  f[4] = __uint_as_float(u.z << 16); f[5] = __uint_as_float(u.z & 0xffff0000u);
  f[6] = __uint_as_float(u.w << 16); f[7] = __uint_as_float(u.w & 0xffff0000u);
}

// ---------- dtype probe (also zeroes the 32 per-group barrier counters) ----------
__global__ void __launch_bounds__(256) k_probe(const uint32_t* __restrict__ w, int* __restrict__ flag,
                                               unsigned* __restrict__ barrs){
  __shared__ int s;
  if (threadIdx.x == 0) s = 0;
  __syncthreads();
  int hit = 0;
  for (int i = threadIdx.x; i < 32768; i += 256){
    uint32_t v = w[i];
    if (((v & 0x7F800000u) == 0x7F800000u) || ((v & 0x00007F80u) == 0x00007F80u)) hit = 1;
  }
  if (hit) atomicOr(&s, 1);
  for (int i = threadIdx.x; i < 1024; i += 256) barrs[i] = 0u;
  __syncthreads();
  if (threadIdx.x == 0) flag[0] = s;
}

// ---------- canonicalize one tensor to bf16 ----------
__global__ void __launch_bounds__(256) k_cvt(const void* __restrict__ src, bf16* __restrict__ dst,
                                             int nquad, const int* __restrict__ flag){
  bool f32 = flag[0] != 0;
  int stride = gridDim.x * 256;
  for (int i = blockIdx.x*256 + threadIdx.x; i < nquad; i += stride){
    if (f32){
      float4 v = reinterpret_cast<const float4*>(src)[i];
      bf16* d = dst + 4*(size_t)i;
      d[0] = __float2bfloat16(v.x); d[1] = __float2bfloat16(v.y);
      d[2] = __float2bfloat16(v.z); d[3] = __float2bfloat16(v.w);
    } else {
      reinterpret_cast<uint2*>(dst)[i] = reinterpret_cast<const uint2*>(src)[i];
    }
  }
}

// ---------- feats[b][p][c] = cnn[b][c][p] ----------
__global__ void __launch_bounds__(256) k_transpose(const bf16* __restrict__ cnn, bf16* __restrict__ feats){
  __shared__ bf16 tile[32][34];
  int ct = blockIdx.x, pt = blockIdx.y, b = blockIdx.z;
  int tid = threadIdx.x;
  int lc = tid >> 5, lp = tid & 31;
  int p = pt*32 + lp;
  #pragma unroll
  for (int i=0;i<4;i++){
    int cc = ct*32 + lc + i*8;
    bf16 v = __float2bfloat16(0.f);
    if (p < PPN) v = cnn[((size_t)b*FEATC + cc)*PPN + p];
    tile[lc + i*8][lp] = v;
  }
  __syncthreads();
  #pragma unroll
  for (int i=0;i<4;i++){
    int pp = pt*32 + lc + i*8;
    if (pp < PPN) feats[((size_t)b*PPN + pp)*FEATC + ct*32 + lp] = tile[lp][lc + i*8];
  }
}

// ---------- WkT = Wk^T (512x512 bf16) ----------
__global__ void __launch_bounds__(256) k_wkt(const bf16* __restrict__ W, bf16* __restrict__ WT){
  __shared__ bf16 tile[32][33];
  const int c0 = blockIdx.x*32, r0 = blockIdx.y*32;
  const int lc = threadIdx.x >> 5, lp = threadIdx.x & 31;
  #pragma unroll
  for (int i=0;i<4;i++) tile[lc + i*8][lp] = W[(size_t)(r0 + lc + i*8)*HIDN + c0 + lp];
  __syncthreads();
  #pragma unroll
  for (int i=0;i<4;i++) WT[(size_t)(c0 + lc + i*8)*HIDN + r0 + lp] = tile[lp][lc + i*8];
}

// ---------- Wcat[r'][0..1280) : r' = j*4+gate, row = [Wih(g*512+j) | Whh(g*512+j)] ----------
__global__ void __launch_bounds__(256) k_wcat(const bf16* __restrict__ Wih, const bf16* __restrict__ Whh,
      const bf16* __restrict__ bih, const bf16* __restrict__ bhh,
      bf16* __restrict__ Wcat, float* __restrict__ biasCat){
  const int rloc = threadIdx.x >> 5, lane32 = threadIdx.x & 31;
  const int r = blockIdx.x*8 + rloc;
  const int j = r >> 2, g = r & 3;
  const int src = g*HIDN + j;
  for (int e4 = lane32; e4 < 320; e4 += 32){
    const int e = e4*4;
    uint2 v = (e < 768) ? *reinterpret_cast<const uint2*>(Wih + (size_t)src*768 + e)
                        : *reinterpret_cast<const uint2*>(Whh + (size_t)src*HIDN + (e - 768));
    *reinterpret_cast<uint2*>(Wcat + (size_t)r*XKN + e) = v;
  }
  if (lane32 == 0) biasCat[r] = b2f(bih[src]) + b2f(bhh[src]);
}

// ---------- g = mean_p cnn ; h0 = g@Wh^T+bh ; c0 = g@Wc^T+bc ----------
__global__ void __launch_bounds__(256) k_init(const bf16* __restrict__ cnn,
      const bf16* __restrict__ Wh, const bf16* __restrict__ bh,
      const bf16* __restrict__ Wc, const bf16* __restrict__ bc,
      float* __restrict__ h, float* __restrict__ c){
  __shared__ float gl[FEATC];
  int b = blockIdx.x, tid = threadIdx.x;
  for (int cc = tid; cc < FEATC; cc += 256){
    const bf16* src = cnn + ((size_t)b*FEATC + cc)*PPN;
    const uint2* sp = reinterpret_cast<const uint2*>(src);
    float acc = 0.f;
    for (int q=0;q<PPN/4;q++){
      uint2 u = sp[q];
      acc += __uint_as_float(u.x<<16) + __uint_as_float(u.x&0xffff0000u)
           + __uint_as_float(u.y<<16) + __uint_as_float(u.y&0xffff0000u);
    }
    gl[cc] = acc * (1.0f/196.0f);
  }
  __syncthreads();
  for (int i = tid; i < HIDN; i += 256){
    const uint4* wr1 = reinterpret_cast<const uint4*>(Wh + (size_t)i*FEATC);
    const uint4* wr2 = reinterpret_cast<const uint4*>(Wc + (size_t)i*FEATC);
    float a1 = 0.f, a2 = 0.f;
    #pragma unroll 4
    for (int k8=0; k8<FEATC/8; k8++){
      float w1[8], w2[8];
      unpack8(wr1[k8], w1); unpack8(wr2[k8], w2);
      const float* gp = &gl[k8*8];
      #pragma unroll
      for (int j=0;j<8;j++){ a1 = fmaf(w1[j], gp[j], a1); a2 = fmaf(w2[j], gp[j], a2); }
    }
    h[b*HIDN+i] = a1 + b2f(bh[i]);
    c[b*HIDN+i] = a2 + b2f(bc[i]);
  }
}

// ---------- initial hk partials from h0 ----------
__global__ void __launch_bounds__(512) k_hk0(const bf16* __restrict__ WkT,
      const float* __restrict__ h, float* __restrict__ part){
  __shared__ float hl[64];
  const int tid = threadIdx.x;
  const int k = blockIdx.x & 7, b = blockIdx.x >> 3;
  if (tid < 64) hl[tid] = h[b*HIDN + k*64 + tid];
  __syncthreads();
  const bf16* wp = WkT + (size_t)(k*64)*AFFN + tid;
  float acc = 0.f;
  #pragma unroll 8
  for (int j=0; j<64; j++) acc = fmaf(b2f(wp[(size_t)j*AFFN]), hl[j], acc);
  part[((size_t)(b*8 + k))*AFFN + tid] = acc;
}

// ---------- generic MFMA GEMM: C[M][N] = A[M][K] @ Bw[N][K]^T (+bias) ----------
// OUTMODE 0: f32 out. 1: dtype by flag (1->f32, 0->bf16). 2: always bf16.
// NT: nontemporal C stores (for large streaming outputs).
template<int OUTMODE, bool BIAS, bool NT>
__global__ void __launch_bounds__(256) gemm_bt(const bf16* __restrict__ A, const bf16* __restrict__ Bw,
        const bf16* __restrict__ bias, void* __restrict__ Cout, int M, int N, int K,
        const int* __restrict__ flag){
  __shared__ __align__(16) bf16 As[64][40];
  __shared__ __align__(16) bf16 Bs[64][40];
  int tid = threadIdx.x;
  int m0 = blockIdx.y*64, n0 = blockIdx.x*64;
  int lr = tid >> 2;
  int lk = (tid & 3)*8;
  int wave = tid >> 6, lane = tid & 63;
  int ml = lane & 15, kg = lane >> 4;
  f32x4 acc0 = {0.f,0.f,0.f,0.f}, acc1 = acc0, acc2 = acc0, acc3 = acc0;
  for (int k0=0; k0<K; k0+=32){
    __syncthreads();
    {
      uint4 av = *reinterpret_cast<const uint4*>(A + (size_t)(m0+lr)*K + k0 + lk);
      *reinterpret_cast<uint4*>(&As[lr][lk]) = av;
      uint4 bv = make_uint4(0u,0u,0u,0u);
      int bn = n0 + lr;
      if (bn < N) bv = *reinterpret_cast<const uint4*>(Bw + (size_t)bn*K + k0 + lk);
      *reinterpret_cast<uint4*>(&Bs[lr][lk]) = bv;
    }
    __syncthreads();
    short8 af = *reinterpret_cast<const short8*>(&As[wave*16 + ml][kg*8]);
    short8 b0 = *reinterpret_cast<const short8*>(&Bs[ 0 + ml][kg*8]);
    short8 b1 = *reinterpret_cast<const short8*>(&Bs[16 + ml][kg*8]);
    short8 b2 = *reinterpret_cast<const short8*>(&Bs[32 + ml][kg*8]);
    short8 b3 = *reinterpret_cast<const short8*>(&Bs[48 + ml][kg*8]);
    acc0 = __builtin_amdgcn_mfma_f32_16x16x32_bf16(af, b0, acc0, 0,0,0);
    acc1 = __builtin_amdgcn_mfma_f32_16x16x32_bf16(af, b1, acc1, 0,0,0);
    acc2 = __builtin_amdgcn_mfma_f32_16x16x32_bf16(af, b2, acc2, 0,0,0);
    acc3 = __builtin_amdgcn_mfma_f32_16x16x32_bf16(af, b3, acc3, 0,0,0);
  }
  bool of32;
  if (OUTMODE == 0) of32 = true;
  else if (OUTMODE == 2) of32 = false;
  else of32 = (flag[0] != 0);
  int mb = m0 + wave*16 + (lane>>4)*4;
  int cl = lane & 15;
  f32x4 av[4] = {acc0, acc1, acc2, acc3};
  #pragma unroll
  for (int j=0;j<4;j++){
    int n = n0 + j*16 + cl;
    if (n < N){
      float bv = BIAS ? b2f(bias[n]) : 0.f;
      #pragma unroll
      for (int rr=0; rr<4; rr++){
        float v = av[j][rr] + bv;
        if (of32){
          float* p = &((float*)Cout)[(size_t)(mb+rr)*N + n];
          if (NT) __builtin_nontemporal_store(v, p); else *p = v;
        } else {
          bf16 hv = __float2bfloat16(v);
          short sv = *reinterpret_cast<short*>(&hv);
          short* p = reinterpret_cast<short*>(&((bf16*)Cout)[(size_t)(mb+rr)*N + n]);
          if (NT) __builtin_nontemporal_store(sv, p); else *p = sv;
        }
      }
    }
  }
}

// ---------- per-b-group barrier: NO cache fences. ----------
// Exchange data uses relaxed agent-scope atomics (coherent at device level),
// so the only ordering needed is vmcnt(0) before signaling + spin on arrival.
__device__ __forceinline__ void gbar(unsigned* ctr, unsigned target){
  __syncthreads();
  if (threadIdx.x == 0){
    asm volatile("s_waitcnt vmcnt(0)" ::: "memory");
    __hip_atomic_fetch_add(ctr, 1u, __ATOMIC_RELAXED, __HIP_MEMORY_SCOPE_AGENT);
    unsigned guard = 0;
    while (__hip_atomic_load(ctr, __ATOMIC_RELAXED, __HIP_MEMORY_SCOPE_AGENT) < target){
      __builtin_amdgcn_s_sleep(1);
      if (++guard > 200000000u) break;   // fail visibly rather than hang
    }
  }
  __syncthreads();
}

// ---------- persistent recurrence kernel ----------
// 256 blocks x 512 threads, 1 block/CU. block (b,k): b = bid>>3, k = bid&7.
// k = bid&7 aligns with the usual XCD = bid%8 mapping -> each XCD hosts ONE
// Wcat k-slice (640 KB), which stays L2-resident all 60 steps (no fences!).
// Cross-block exchange (part/Vpart/mS/hstate) is all within a b-group of 8
// blocks, via relaxed agent atomics + per-group barriers (2 per step).
__global__ void __launch_bounds__(512) k_pers(
    const bf16* __restrict__ kvB, const bf16* __restrict__ feats,
    const bf16* __restrict__ WkT, const bf16* __restrict__ Wcat,
    const float* __restrict__ biasCat, const bf16* __restrict__ wa,
    const bf16* __restrict__ table, const int* __restrict__ captions,
    float* __restrict__ hstate,          // [2][32][512] parity dbuf
    const float* __restrict__ cinit,     // [32][512]
    float* __restrict__ part,            // [32][8][512]
    float* __restrict__ Vpart,           // [32][8][512]
    float* __restrict__ mS,              // [32][8][2]
    bf16* __restrict__ Hb, unsigned* __restrict__ barrs)
{
  __shared__ __align__(16) bf16 kv_s[25][512];
  __shared__ __align__(16) bf16 ft_s[25][512];
  __shared__ __align__(16) float xs[XKN];
  __shared__ __align__(16) float hks[AFFN];
  __shared__ float gs[256];
  __shared__ float zes[32];
  __shared__ float es[32];
  __shared__ float hnew[64];

  const int tid = threadIdx.x;
  const int bid = blockIdx.x;
  const int k = bid & 7, b = bid >> 3;
  unsigned* ctr = barrs + b*32;          // 128 B apart -> no false sharing
  const int np = (k < 4) ? 25 : 24;
  const int p0 = (k < 4) ? k*25 : 100 + (k-4)*24;
  const int lane = tid & 63, wv = tid >> 6;

  // ---- prologue: stage kv/feats p-slice into LDS (once, reused 60 steps) ----
  {
    const uint4* kvg = reinterpret_cast<const uint4*>(kvB + ((size_t)(b*PPN + p0))*AFFN);
    const uint4* ftg = reinterpret_cast<const uint4*>(feats + ((size_t)(b*PPN + p0))*FEATC);
    uint4* kvl = reinterpret_cast<uint4*>(&kv_s[0][0]);
    uint4* ftl = reinterpret_cast<uint4*>(&ft_s[0][0]);
    const int nq = np*64;
    for (int i = tid; i < nq; i += 512){ kvl[i] = kvg[i]; ftl[i] = ftg[i]; }
  }
  float creg = 0.f;
  if (tid < 64) creg = cinit[b*HIDN + k*64 + tid];
  float wf[8];
  unpack8(*reinterpret_cast<const uint4*>(wa + lane*8), wf);
  __syncthreads();

  unsigned bexp = 0;
  for (int t = 0; t < TTN; t++){
    // ================= Phase A =================
    // hk[a] = sum of 8 partials (written last step phase B, across barrier B)
    {
      const float* pp = part + (size_t)b*8*AFFN + tid;
      float s = 0.f;
      #pragma unroll
      for (int kk=0; kk<8; kk++) s += aload(pp + (size_t)kk*AFFN);
      hks[tid] = s;
    }
    if (tid < EMBN){
      const int tok = captions[b*TTN + t];
      xs[tid] = b2f(table[(size_t)tok*EMBN + tid]);
    }
    __syncthreads();

    // z for my p-slice (wave per p), kv from LDS
    {
      float hf[8];
      const float4* hp = reinterpret_cast<const float4*>(&hks[lane*8]);
      float4 t0 = hp[0], t1 = hp[1];
      hf[0]=t0.x; hf[1]=t0.y; hf[2]=t0.z; hf[3]=t0.w;
      hf[4]=t1.x; hf[5]=t1.y; hf[6]=t1.z; hf[7]=t1.w;
      for (int pl = wv; pl < np; pl += 8){
        float kf[8]; unpack8(*reinterpret_cast<const uint4*>(&kv_s[pl][lane*8]), kf);
        float acc = wf[0]*ftanhf(kf[0]+hf[0]) + wf[1]*ftanhf(kf[1]+hf[1])
                  + wf[2]*ftanhf(kf[2]+hf[2]) + wf[3]*ftanhf(kf[3]+hf[3])
                  + wf[4]*ftanhf(kf[4]+hf[4]) + wf[5]*ftanhf(kf[5]+hf[5])
                  + wf[6]*ftanhf(kf[6]+hf[6]) + wf[7]*ftanhf(kf[7]+hf[7]);
        #pragma unroll
        for (int s=1;s<64;s<<=1) acc += __shfl_xor(acc, s, 64);
        if (lane == 0) zes[pl] = acc;
      }
    }
    __syncthreads();

    // partial softmax over my np z's (wave 0): m_k, S_k, es[]
    if (wv == 0){
      float v = (lane < np) ? zes[lane] : -1e30f;
      float m = v;
      #pragma unroll
      for (int s=1;s<64;s<<=1) m = fmaxf(m, __shfl_xor(m, s, 64));
      float e = (lane < np) ? fexp2((v - m)*1.4426950408889634f) : 0.f;
      float ssum = e;
      #pragma unroll
      for (int s=1;s<64;s<<=1) ssum += __shfl_xor(ssum, s, 64);
      if (lane < np) es[lane] = e;
      if (lane == 0){ astore(&mS[(b*8+k)*2 + 0], m); astore(&mS[(b*8+k)*2 + 1], ssum); }
    }
    __syncthreads();

    // V_k[c] = sum_{p in slice} e_p * feats[p][c]  (feats from LDS)
    {
      float acc = 0.f;
      #pragma unroll 4
      for (int pl=0; pl<np; pl++) acc = fmaf(es[pl], b2f(ft_s[pl][tid]), acc);
      astore(&Vpart[((size_t)(b*8+k))*FEATC + tid], acc);
    }

    bexp += 8; gbar(ctr, bexp);   // -------- barrier A (group of 8) --------

    // ================= Phase B =================
    // combine slice partials -> ctx; gather h (parity-old)
    {
      const float* msb = mS + b*16;
      float mk[8], sk[8], m = -1e30f;
      #pragma unroll
      for (int kk=0;kk<8;kk++){ mk[kk] = aload(msb + kk*2); sk[kk] = aload(msb + kk*2 + 1); m = fmaxf(m, mk[kk]); }
      float Z = 0.f, w[8];
      #pragma unroll
      for (int kk=0;kk<8;kk++){ w[kk] = fexp2((mk[kk]-m)*1.4426950408889634f); Z = fmaf(sk[kk], w[kk], Z); }
      const float inv = 1.0f / Z;
      float acc = 0.f;
      const float* vp = Vpart + (size_t)b*8*FEATC + tid;
      #pragma unroll
      for (int kk=0;kk<8;kk++) acc = fmaf(w[kk], aload(vp + (size_t)kk*FEATC), acc);
      xs[EMBN + tid] = acc * inv;
      xs[EMBN + FEATC + tid] = aload(&hstate[(size_t)(t&1)*BB*HIDN + b*HIDN + tid]);
    }
    __syncthreads();

    // gates: 2 threads per row (k-halves), rows k*256 + r, r = j*4+gate
    // Wcat slice is plain-cached: stays hot in this XCD's L2 across all steps
    {
      const int r = tid >> 1, half = tid & 1;
      const int rowg = k*256 + r;
      const bf16* wrow = Wcat + (size_t)rowg*XKN + half*640;
      const float* xp = xs + half*640;
      float a0=0.f,a1=0.f,a2=0.f,a3=0.f;
      #pragma unroll 4
      for (int e=0; e<640; e+=8){
        float w8[8]; unpack8(*reinterpret_cast<const uint4*>(wrow + e), w8);
        float4 x0 = *reinterpret_cast<const float4*>(xp + e);
        float4 x1 = *reinterpret_cast<const float4*>(xp + e + 4);
        a0 = fmaf(w8[0],x0.x,a0); a1 = fmaf(w8[1],x0.y,a1);
        a2 = fmaf(w8[2],x0.z,a2); a3 = fmaf(w8[3],x0.w,a3);
        a0 = fmaf(w8[4],x1.x,a0); a1 = fmaf(w8[5],x1.y,a1);
        a2 = fmaf(w8[6],x1.z,a2); a3 = fmaf(w8[7],x1.w,a3);
      }
      float acc = (a0+a1)+(a2+a3);
      acc += __shfl_xor(acc, 1, 64);
      if (half == 0) gs[r] = acc + biasCat[rowg];
    }
    __syncthreads();

    // cell update for my 64 j's (c in registers)
    if (tid < 64){
      const int j = k*64 + tid;
      float gi = gs[tid*4+0], gf = gs[tid*4+1], gg = gs[tid*4+2], go = gs[tid*4+3];
      float cn = fsig(gf)*creg + fsig(gi)*ftanhf(gg);
      float hn = fsig(go)*ftanhf(cn);
      creg = cn;
      astore(&hstate[(size_t)((t+1)&1)*BB*HIDN + b*HIDN + j], hn);
      Hb[((size_t)b*TTN + t)*HIDN + j] = __float2bfloat16(hn);
      hnew[tid] = hn;
    }
    __syncthreads();

    // next step's hk partial over my h slice (WkT slice L2-resident)
    {
      const bf16* wp = WkT + (size_t)(k*64)*AFFN + tid;
      float acc = 0.f;
      #pragma unroll 8
      for (int j=0;j<64;j++) acc = fmaf(b2f(wp[(size_t)j*AFFN]), hnew[j], acc);
      astore(&part[((size_t)(b*8+k))*AFFN + tid], acc);
    }

    bexp += 8; gbar(ctr, bexp);   // -------- barrier B (group of 8) --------
  }
}

static inline int cvt_grid(int nquad){ int g = (nquad + 255)/256; return g > 1024 ? 1024 : g; }

extern "C" void kernel_launch(void* const* d_in, const int* in_sizes, int n_in,
                              void* d_out, int out_size, void* d_ws, size_t ws_size,
                              hipStream_t stream) {
  const int* captions = (const int*)d_in[1];
  char* ws = (char*)d_ws;

  // ---- workspace layout (bytes) ----
  bf16*  feats  = (bf16*) (ws + 0);           // [6272][512] bf16
  bf16*  kvB    = (bf16*) (ws + 6422528);     // [6272][512] bf16
  float* hstate = (float*)(ws + 12845056);    // [2][32][512] f32
  float* cstate = (float*)(ws + 12976128);    // [32][512] f32
  float* part   = (float*)(ws + 13041664);    // [32][8][512] f32
  float* Vpart  = (float*)(ws + 13565952);    // [32][8][512] f32
  float* mS     = (float*)(ws + 14090240);    // [32][8][2] f32
  unsigned* barrs=(unsigned*)(ws + 14092416); // 32 counters, 128B apart (4 KB)
  bf16*  Hb     = (bf16*) (ws + 14096512);    // [32][60][512] bf16
  bf16*  cnnB   = (bf16*) (ws + 16062592);    // [32][512][196] bf16 (dead after transpose+init)
  bf16*  WcatB  = (bf16*) (ws + 16062592);    // [2048][1280] bf16 — ALIASES cnnB
  bf16*  tableB = (bf16*) (ws + 22485120);
  bf16*  WkB    = (bf16*) (ws + 27605120);
  bf16*  WkTB   = (bf16*) (ws + 28129408);
  bf16*  WvB    = (bf16*) (ws + 28653696);
  bf16*  WhB    = (bf16*) (ws + 29177984);
  bf16*  WcB    = (bf16*) (ws + 29702272);
  bf16*  WihB   = (bf16*) (ws + 30226560);
  bf16*  WhhB   = (bf16*) (ws + 33372288);
  bf16*  WfcB   = (bf16*) (ws + 35469440);
  bf16*  waB    = (bf16*) (ws + 45709440);
  bf16*  bhB    = (bf16*) (ws + 45710464);
  bf16*  bcB    = (bf16*) (ws + 45711488);
  bf16*  bihB   = (bf16*) (ws + 45712512);
  bf16*  bhhB   = (bf16*) (ws + 45716608);
  bf16*  bfcB   = (bf16*) (ws + 45720704);
  float* biasCat= (float*)(ws + 45740704);
  int*   flag   = (int*)  (ws + 45748896);
  if (ws_size < 45748912ull) return;

  // 1) dtype probe + barrier reset
  k_probe<<<1, 256, 0, stream>>>((const uint32_t*)d_in[5], flag, barrs);

  // 2) canonicalize to bf16
  struct CvtJob { const void* src; bf16* dst; int n; };
  const CvtJob jobs[15] = {
    {d_in[0],  cnnB,   3211264}, {d_in[2],  WkB,  262144}, {d_in[3],  WvB,  262144},
    {d_in[4],  waB,    512},     {d_in[5],  tableB, 2560000},
    {d_in[6],  WhB,    262144},  {d_in[7],  bhB,  512},
    {d_in[8],  WcB,    262144},  {d_in[9],  bcB,  512},
    {d_in[10], WihB,   1572864}, {d_in[11], WhhB, 1048576},
    {d_in[12], bihB,   2048},    {d_in[13], bhhB, 2048},
    {d_in[14], WfcB,   5120000}, {d_in[15], bfcB, 10000},
  };
  for (int i = 0; i < 15; i++){
    int nq = jobs[i].n / 4;
    k_cvt<<<cvt_grid(nq), 256, 0, stream>>>(jobs[i].src, jobs[i].dst, nq, flag);
  }

  // 3) precompute (cnnB consumers run BEFORE k_wcat overwrites that region)
  k_transpose<<<dim3(16,7,32), 256, 0, stream>>>(cnnB, feats);
  k_init<<<32, 256, 0, stream>>>(cnnB, WhB, bhB, WcB, bcB, hstate, cstate);  // parity 0
  k_wkt<<<dim3(16,16), 256, 0, stream>>>(WkB, WkTB);
  k_wcat<<<256, 256, 0, stream>>>(WihB, WhhB, bihB, bhhB, WcatB, biasCat);
  k_hk0<<<256, 512, 0, stream>>>(WkTB, hstate, part);
  gemm_bt<2,false,false><<<dim3(8,98), 256, 0, stream>>>(feats, WvB, (const bf16*)nullptr,
                                                   (void*)kvB, 6272, 512, 512, (const int*)nullptr);

  // 4) the whole recurrence: ONE persistent kernel, fence-free group barriers
  k_pers<<<256, 512, 0, stream>>>(kvB, feats, WkTB, WcatB, biasCat, waB, tableB,
                                  captions, hstate, cstate, part, Vpart, mS, Hb, barrs);

  // 5) logits = Hb @ Wfc^T + bfc (nontemporal C stores: don't thrash L2)
  gemm_bt<1,true,true><<<dim3(157,30), 256, 0, stream>>>(Hb, WfcB, bfcB, d_out,
                                                    1920, 10000, 512, flag);
}

// Round 5
// 1902.638 us; speedup vs baseline: 2.5707x; 1.0195x over previous
//
#include <hip/hip_runtime.h>
#include <hip/hip_bf16.h>
#include <cstdint>
#include <cstddef>

#define VOCABN 10000
#define FEATC 512
#define EMBN 256
#define HIDN 512
#define AFFN 512
#define BB 32
#define TTN 60
#define PPN 196
#define XKN 1280   // x layout per batch: emb[0,256) | ctx[256,768) | h[768,1280)

using bf16 = __hip_bfloat16;

typedef __attribute__((ext_vector_type(8))) short short8;
typedef __attribute__((ext_vector_type(4))) float f32x4;

__device__ __forceinline__ float b2f(bf16 x){ return __bfloat162float(x); }
__device__ __forceinline__ float fexp2(float x){ return __builtin_amdgcn_exp2f(x); }
__device__ __forceinline__ float frcp(float x){ return __builtin_amdgcn_rcpf(x); }
__device__ __forceinline__ float fsig(float x){ return frcp(1.f + fexp2(-1.4426950408889634f*x)); }
__device__ __forceinline__ float ftanhf(float x){ return 1.f - 2.f*frcp(1.f + fexp2(2.8853900817779268f*x)); }

// relaxed agent-scope accessors: device-coherent (serviced at the coherence
// point), no cache-maintenance fences.
__device__ __forceinline__ float aload(const float* p){
  return __hip_atomic_load((float*)p, __ATOMIC_RELAXED, __HIP_MEMORY_SCOPE_AGENT);
}
__device__ __forceinline__ void astore(float* p, float v){
  __hip_atomic_store(p, v, __ATOMIC_RELAXED, __HIP_MEMORY_SCOPE_AGENT);
}
__device__ __forceinline__ void astoreu(unsigned* p, unsigned v){
  __hip_atomic_store(p, v, __ATOMIC_RELAXED, __HIP_MEMORY_SCOPE_AGENT);
}
__device__ __forceinline__ unsigned aloadu(const unsigned* p){
  return __hip_atomic_load((unsigned*)p, __ATOMIC_RELAXED, __HIP_MEMORY_SCOPE_AGENT);
}

// 16B coherent load/store: same cache-control (sc0 sc1) the compiler emits for
// agent-scope atomics, but dwordx4-wide. f32x4 (ext_vector) binds to a VGPR
// quad -- HIP's float4 struct does NOT compile under the "v" constraint.
// Loads are async: issue N, then ic_wait() before using results (rule #18).
__device__ __forceinline__ f32x4 ic_load4(const float* p){
  f32x4 r;
  asm volatile("global_load_dwordx4 %0, %1, off sc0 sc1" : "=&v"(r) : "v"(p));
  return r;
}
__device__ __forceinline__ void ic_store4(float* p, f32x4 v){
  asm volatile("global_store_dwordx4 %0, %1, off sc0 sc1" :: "v"(p), "v"(v) : "memory");
}
__device__ __forceinline__ void ic_wait(){
  asm volatile("s_waitcnt vmcnt(0)" ::: "memory");
  __builtin_amdgcn_sched_barrier(0);   // rule #18: keep uses below the wait
}

__device__ __forceinline__ void unpack8(uint4 u, float* f){
  f[0] = __uint_as_float(u.x << 16); f[1] = __uint_as_float(u.x & 0xffff0000u);
  f[2] = __uint_as_float(u.y << 16); f[3] = __uint_as_float(u.y & 0xffff0000u);
  f[4] = __uint_as_float(u.z << 16); f[5] = __uint_as_float(u.z & 0xffff0000u);
  f[6] = __uint_as_float(u.w << 16); f[7] = __uint_as_float(u.w & 0xffff0000u);
}

// ---------- dtype probe (also zeroes the per-group barrier flags, coherently) ----------
__global__ void __launch_bounds__(256) k_probe(const uint32_t* __restrict__ w, int* __restrict__ flag,
                                               unsigned* __restrict__ flags){
  __shared__ int s;
  if (threadIdx.x == 0) s = 0;
  __syncthreads();
  int hit = 0;
  for (int i = threadIdx.x; i < 32768; i += 256){
    uint32_t v = w[i];
    if (((v & 0x7F800000u) == 0x7F800000u) || ((v & 0x00007F80u) == 0x00007F80u)) hit = 1;
  }
  if (hit) atomicOr(&s, 1);
  for (int i = threadIdx.x; i < 1024; i += 256) astoreu(&flags[i], 0u);
  __syncthreads();
  if (threadIdx.x == 0) flag[0] = s;
}

// ---------- canonicalize one tensor to bf16 ----------
__global__ void __launch_bounds__(256) k_cvt(const void* __restrict__ src, bf16* __restrict__ dst,
                                             int nquad, const int* __restrict__ flag){
  bool f32 = flag[0] != 0;
  int stride = gridDim.x * 256;
  for (int i = blockIdx.x*256 + threadIdx.x; i < nquad; i += stride){
    if (f32){
      float4 v = reinterpret_cast<const float4*>(src)[i];
      bf16* d = dst + 4*(size_t)i;
      d[0] = __float2bfloat16(v.x); d[1] = __float2bfloat16(v.y);
      d[2] = __float2bfloat16(v.z); d[3] = __float2bfloat16(v.w);
    } else {
      reinterpret_cast<uint2*>(dst)[i] = reinterpret_cast<const uint2*>(src)[i];
    }
  }
}

// ---------- feats[b][p][c] = cnn[b][c][p] ----------
__global__ void __launch_bounds__(256) k_transpose(const bf16* __restrict__ cnn, bf16* __restrict__ feats){
  __shared__ bf16 tile[32][34];
  int ct = blockIdx.x, pt = blockIdx.y, b = blockIdx.z;
  int tid = threadIdx.x;
  int lc = tid >> 5, lp = tid & 31;
  int p = pt*32 + lp;
  #pragma unroll
  for (int i=0;i<4;i++){
    int cc = ct*32 + lc + i*8;
    bf16 v = __float2bfloat16(0.f);
    if (p < PPN) v = cnn[((size_t)b*FEATC + cc)*PPN + p];
    tile[lc + i*8][lp] = v;
  }
  __syncthreads();
  #pragma unroll
  for (int i=0;i<4;i++){
    int pp = pt*32 + lc + i*8;
    if (pp < PPN) feats[((size_t)b*PPN + pp)*FEATC + ct*32 + lp] = tile[lp][lc + i*8];
  }
}

// ---------- WkT = Wk^T (512x512 bf16) ----------
__global__ void __launch_bounds__(256) k_wkt(const bf16* __restrict__ W, bf16* __restrict__ WT){
  __shared__ bf16 tile[32][33];
  const int c0 = blockIdx.x*32, r0 = blockIdx.y*32;
  const int lc = threadIdx.x >> 5, lp = threadIdx.x & 31;
  #pragma unroll
  for (int i=0;i<4;i++) tile[lc + i*8][lp] = W[(size_t)(r0 + lc + i*8)*HIDN + c0 + lp];
  __syncthreads();
  #pragma unroll
  for (int i=0;i<4;i++) WT[(size_t)(c0 + lc + i*8)*HIDN + r0 + lp] = tile[lp][lc + i*8];
}

// ---------- Wcat[r'][0..1280) : r' = j*4+gate, row = [Wih(g*512+j) | Whh(g*512+j)] ----------
__global__ void __launch_bounds__(256) k_wcat(const bf16* __restrict__ Wih, const bf16* __restrict__ Whh,
      const bf16* __restrict__ bih, const bf16* __restrict__ bhh,
      bf16* __restrict__ Wcat, float* __restrict__ biasCat){
  const int rloc = threadIdx.x >> 5, lane32 = threadIdx.x & 31;
  const int r = blockIdx.x*8 + rloc;
  const int j = r >> 2, g = r & 3;
  const int src = g*HIDN + j;
  for (int e4 = lane32; e4 < 320; e4 += 32){
    const int e = e4*4;
    uint2 v = (e < 768) ? *reinterpret_cast<const uint2*>(Wih + (size_t)src*768 + e)
                        : *reinterpret_cast<const uint2*>(Whh + (size_t)src*HIDN + (e - 768));
    *reinterpret_cast<uint2*>(Wcat + (size_t)r*XKN + e) = v;
  }
  if (lane32 == 0) biasCat[r] = b2f(bih[src]) + b2f(bhh[src]);
}

// ---------- g = mean_p cnn ; h0 = g@Wh^T+bh ; c0 = g@Wc^T+bc (published coherently) ----------
__global__ void __launch_bounds__(256) k_init(const bf16* __restrict__ cnn,
      const bf16* __restrict__ Wh, const bf16* __restrict__ bh,
      const bf16* __restrict__ Wc, const bf16* __restrict__ bc,
      float* __restrict__ h, float* __restrict__ c){
  __shared__ float gl[FEATC];
  int b = blockIdx.x, tid = threadIdx.x;
  for (int cc = tid; cc < FEATC; cc += 256){
    const bf16* src = cnn + ((size_t)b*FEATC + cc)*PPN;
    const uint2* sp = reinterpret_cast<const uint2*>(src);
    float acc = 0.f;
    for (int q=0;q<PPN/4;q++){
      uint2 u = sp[q];
      acc += __uint_as_float(u.x<<16) + __uint_as_float(u.x&0xffff0000u)
           + __uint_as_float(u.y<<16) + __uint_as_float(u.y&0xffff0000u);
    }
    gl[cc] = acc * (1.0f/196.0f);
  }
  __syncthreads();
  for (int i = tid; i < HIDN; i += 256){
    const uint4* wr1 = reinterpret_cast<const uint4*>(Wh + (size_t)i*FEATC);
    const uint4* wr2 = reinterpret_cast<const uint4*>(Wc + (size_t)i*FEATC);
    float a1 = 0.f, a2 = 0.f;
    #pragma unroll 4
    for (int k8=0; k8<FEATC/8; k8++){
      float w1[8], w2[8];
      unpack8(wr1[k8], w1); unpack8(wr2[k8], w2);
      const float* gp = &gl[k8*8];
      #pragma unroll
      for (int j=0;j<8;j++){ a1 = fmaf(w1[j], gp[j], a1); a2 = fmaf(w2[j], gp[j], a2); }
    }
    astore(&h[b*HIDN+i], a1 + b2f(bh[i]));
    astore(&c[b*HIDN+i], a2 + b2f(bc[i]));
  }
}

// ---------- initial hk partials from h0 (published coherently) ----------
__global__ void __launch_bounds__(512) k_hk0(const bf16* __restrict__ WkT,
      const float* __restrict__ h, float* __restrict__ part){
  __shared__ float hl[64];
  const int tid = threadIdx.x;
  const int k = blockIdx.x & 7, b = blockIdx.x >> 3;
  if (tid < 64) hl[tid] = aload(&h[b*HIDN + k*64 + tid]);
  __syncthreads();
  const bf16* wp = WkT + (size_t)(k*64)*AFFN + tid;
  float acc = 0.f;
  #pragma unroll 8
  for (int j=0; j<64; j++) acc = fmaf(b2f(wp[(size_t)j*AFFN]), hl[j], acc);
  astore(&part[((size_t)(b*8 + k))*AFFN + tid], acc);
}

// ---------- generic MFMA GEMM: C[M][N] = A[M][K] @ Bw[N][K]^T (+bias) ----------
template<int OUTMODE, bool BIAS, bool NT>
__global__ void __launch_bounds__(256) gemm_bt(const bf16* __restrict__ A, const bf16* __restrict__ Bw,
        const bf16* __restrict__ bias, void* __restrict__ Cout, int M, int N, int K,
        const int* __restrict__ flag){
  __shared__ __align__(16) bf16 As[64][40];
  __shared__ __align__(16) bf16 Bs[64][40];
  int tid = threadIdx.x;
  int m0 = blockIdx.y*64, n0 = blockIdx.x*64;
  int lr = tid >> 2;
  int lk = (tid & 3)*8;
  int wave = tid >> 6, lane = tid & 63;
  int ml = lane & 15, kg = lane >> 4;
  f32x4 acc0 = {0.f,0.f,0.f,0.f}, acc1 = acc0, acc2 = acc0, acc3 = acc0;
  for (int k0=0; k0<K; k0+=32){
    __syncthreads();
    {
      uint4 av = *reinterpret_cast<const uint4*>(A + (size_t)(m0+lr)*K + k0 + lk);
      *reinterpret_cast<uint4*>(&As[lr][lk]) = av;
      uint4 bv = make_uint4(0u,0u,0u,0u);
      int bn = n0 + lr;
      if (bn < N) bv = *reinterpret_cast<const uint4*>(Bw + (size_t)bn*K + k0 + lk);
      *reinterpret_cast<uint4*>(&Bs[lr][lk]) = bv;
    }
    __syncthreads();
    short8 af = *reinterpret_cast<const short8*>(&As[wave*16 + ml][kg*8]);
    short8 b0 = *reinterpret_cast<const short8*>(&Bs[ 0 + ml][kg*8]);
    short8 b1 = *reinterpret_cast<const short8*>(&Bs[16 + ml][kg*8]);
    short8 b2 = *reinterpret_cast<const short8*>(&Bs[32 + ml][kg*8]);
    short8 b3 = *reinterpret_cast<const short8*>(&Bs[48 + ml][kg*8]);
    acc0 = __builtin_amdgcn_mfma_f32_16x16x32_bf16(af, b0, acc0, 0,0,0);
    acc1 = __builtin_amdgcn_mfma_f32_16x16x32_bf16(af, b1, acc1, 0,0,0);
    acc2 = __builtin_amdgcn_mfma_f32_16x16x32_bf16(af, b2, acc2, 0,0,0);
    acc3 = __builtin_amdgcn_mfma_f32_16x16x32_bf16(af, b3, acc3, 0,0,0);
  }
  bool of32;
  if (OUTMODE == 0) of32 = true;
  else if (OUTMODE == 2) of32 = false;
  else of32 = (flag[0] != 0);
  int mb = m0 + wave*16 + (lane>>4)*4;
  int cl = lane & 15;
  f32x4 av[4] = {acc0, acc1, acc2, acc3};
  #pragma unroll
  for (int j=0;j<4;j++){
    int n = n0 + j*16 + cl;
    if (n < N){
      float bv = BIAS ? b2f(bias[n]) : 0.f;
      #pragma unroll
      for (int rr=0; rr<4; rr++){
        float v = av[j][rr] + bv;
        if (of32){
          float* p = &((float*)Cout)[(size_t)(mb+rr)*N + n];
          if (NT) __builtin_nontemporal_store(v, p); else *p = v;
        } else {
          bf16 hv = __float2bfloat16(v);
          short sv = *reinterpret_cast<short*>(&hv);
          short* p = reinterpret_cast<short*>(&((bf16*)Cout)[(size_t)(mb+rr)*N + n]);
          if (NT) __builtin_nontemporal_store(sv, p); else *p = sv;
        }
      }
    }
  }
}

// ---------- per-b-group flag barrier: store-only arrival, lane-parallel poll ----------
// EVERY wave drains its own vmcnt first (fixes the single-wave-drain race), then
// one relaxed agent store (no RMW serialization), then all waves poll 8 flags.
__device__ __forceinline__ void fbar(unsigned* f8, int myk, unsigned token){
  asm volatile("s_waitcnt vmcnt(0)" ::: "memory");
  __syncthreads();
  if (threadIdx.x == 0) astoreu(&f8[myk], token);
  {
    const int lane = threadIdx.x & 63;
    unsigned guard = 0;
    for (;;){
      unsigned v = (lane < 8) ? aloadu(&f8[lane]) : token;
      if (__all((int)(v >= token))) break;
      if (++guard > 50000000u) break;   // fail visibly rather than hang
      __builtin_amdgcn_s_sleep(2);
    }
  }
  __syncthreads();
}

// gate partial accumulator over [x+0, x+len) columns
__device__ __forceinline__ void gacc(const bf16* w, const float* x, int len,
                                     float& a0, float& a1, float& a2, float& a3){
  #pragma unroll 4
  for (int e=0; e<len; e+=8){
    float w8[8]; unpack8(*reinterpret_cast<const uint4*>(w+e), w8);
    float4 x0 = *reinterpret_cast<const float4*>(x+e);
    float4 x1 = *reinterpret_cast<const float4*>(x+e+4);
    a0 = fmaf(w8[0],x0.x,a0); a1 = fmaf(w8[1],x0.y,a1);
    a2 = fmaf(w8[2],x0.z,a2); a3 = fmaf(w8[3],x0.w,a3);
    a0 = fmaf(w8[4],x1.x,a0); a1 = fmaf(w8[5],x1.y,a1);
    a2 = fmaf(w8[6],x1.z,a2); a3 = fmaf(w8[7],x1.w,a3);
  }
}

// ---------- persistent recurrence kernel ----------
// 256 blocks x 512 threads. block (b,k): b = bid>>3, k = bid&7 (k aligns with
// XCD=bid%8 -> one Wcat k-slice per XCD, L2-resident all 60 steps).
// All cross-block exchange is 16B sc0/sc1 (coherence-point) transfers.
__global__ void __launch_bounds__(512) k_pers(
    const bf16* __restrict__ kvB, const bf16* __restrict__ feats,
    const bf16* __restrict__ WkT, const bf16* __restrict__ Wcat,
    const float* __restrict__ biasCat, const bf16* __restrict__ wa,
    const bf16* __restrict__ table, const int* __restrict__ captions,
    float* __restrict__ hstate,          // [32][512] (single buffer; barrier-ordered)
    const float* __restrict__ cinit,     // [32][512]
    float* __restrict__ part,            // [32][8][512]
    float* __restrict__ Vpart,           // [32][8][512]
    float* __restrict__ mS,              // [32][8][2]
    bf16* __restrict__ Hb, unsigned* __restrict__ flags)
{
  __shared__ __align__(16) bf16 kv_s[25][512];
  __shared__ __align__(16) bf16 ft_s[25][512];
  __shared__ __align__(16) float xs[XKN];
  __shared__ __align__(16) float hks[AFFN];   // hk; reused as f32 staging scratch
  __shared__ float gs[256];
  __shared__ float zes[32];
  __shared__ float es[32];
  __shared__ float msl[16];
  __shared__ __align__(16) float hnew[64];

  const int tid = threadIdx.x;
  const int bid = blockIdx.x;
  const int k = bid & 7, b = bid >> 3;
  unsigned* fl = flags + b*32;           // 8 used, 128 B stride per group
  const int np = (k < 4) ? 25 : 24;
  const int p0 = (k < 4) ? k*25 : 100 + (k-4)*24;
  const int lane = tid & 63, wv = tid >> 6;

  // gate-row assignment: 2 threads per row, branch-free split of 1280 cols:
  // pre-barrier (emb|h, 768 cols): half0 [0,256)+[768,896), half1 [896,1152)+[1152,1280)
  // post-barrier (ctx, 512 cols): half0 [256,512), half1 [512,768)
  const int r2 = tid >> 1, half = tid & 1;
  const int rowg = k*256 + r2;
  const bf16* wrow = Wcat + (size_t)rowg*XKN;
  const int s1 = half*896;
  const int s2 = 768 + half*384;
  const int s3 = 256 + half*256;

  // ---- prologue: stage kv/feats p-slice into LDS (once, reused 60 steps) ----
  {
    const uint4* kvg = reinterpret_cast<const uint4*>(kvB + ((size_t)(b*PPN + p0))*AFFN);
    const uint4* ftg = reinterpret_cast<const uint4*>(feats + ((size_t)(b*PPN + p0))*FEATC);
    uint4* kvl = reinterpret_cast<uint4*>(&kv_s[0][0]);
    uint4* ftl = reinterpret_cast<uint4*>(&ft_s[0][0]);
    const int nq = np*64;
    for (int i = tid; i < nq; i += 512){ kvl[i] = kvg[i]; ftl[i] = ftg[i]; }
  }
  float creg = 0.f;
  if (tid < 64) creg = cinit[b*HIDN + k*64 + tid];
  float wf[8];
  unpack8(*reinterpret_cast<const uint4*>(wa + lane*8), wf);
  __syncthreads();

  for (int t = 0; t < TTN; t++){
    // ================= Phase A =================
    // A0: batched coherent loads: hk partials (tid<128), h (tid 128..255), emb (tid 256+)
    f32x4 pq[8]; f32x4 hq;
    if (tid < 128){
      const float* pp = part + (size_t)b*8*AFFN + tid*4;
      #pragma unroll
      for (int kk=0;kk<8;kk++) pq[kk] = ic_load4(pp + (size_t)kk*AFFN);
    } else if (tid < 256){
      hq = ic_load4(hstate + (size_t)b*HIDN + (tid-128)*4);
    } else {
      const int tok = captions[b*TTN + t];
      xs[tid-256] = b2f(table[(size_t)tok*EMBN + (tid-256)]);
    }
    ic_wait();
    if (tid < 128){
      f32x4 s = pq[0];
      #pragma unroll
      for (int kk=1;kk<8;kk++) s += pq[kk];
      *reinterpret_cast<f32x4*>(&hks[tid*4]) = s;
    } else if (tid < 256){
      *reinterpret_cast<f32x4*>(&xs[EMBN+FEATC+(tid-128)*4]) = hq;
    }
    __syncthreads();

    // A1: z for my p-slice (wave per p), kv from LDS
    {
      float hf[8];
      const float4* hp = reinterpret_cast<const float4*>(&hks[lane*8]);
      float4 t0 = hp[0], t1 = hp[1];
      hf[0]=t0.x; hf[1]=t0.y; hf[2]=t0.z; hf[3]=t0.w;
      hf[4]=t1.x; hf[5]=t1.y; hf[6]=t1.z; hf[7]=t1.w;
      for (int pl = wv; pl < np; pl += 8){
        float kf[8]; unpack8(*reinterpret_cast<const uint4*>(&kv_s[pl][lane*8]), kf);
        float acc = wf[0]*ftanhf(kf[0]+hf[0]) + wf[1]*ftanhf(kf[1]+hf[1])
                  + wf[2]*ftanhf(kf[2]+hf[2]) + wf[3]*ftanhf(kf[3]+hf[3])
                  + wf[4]*ftanhf(kf[4]+hf[4]) + wf[5]*ftanhf(kf[5]+hf[5])
                  + wf[6]*ftanhf(kf[6]+hf[6]) + wf[7]*ftanhf(kf[7]+hf[7]);
        #pragma unroll
        for (int s=1;s<64;s<<=1) acc += __shfl_xor(acc, s, 64);
        if (lane == 0) zes[pl] = acc;
      }
    }
    __syncthreads();

    // A2: partial softmax over my np z's (wave 0): m_k, S_k, es[]
    if (wv == 0){
      float v = (lane < np) ? zes[lane] : -1e30f;
      float m = v;
      #pragma unroll
      for (int s=1;s<64;s<<=1) m = fmaxf(m, __shfl_xor(m, s, 64));
      float e = (lane < np) ? fexp2((v - m)*1.4426950408889634f) : 0.f;
      float ssum = e;
      #pragma unroll
      for (int s=1;s<64;s<<=1) ssum += __shfl_xor(ssum, s, 64);
      if (lane < np) es[lane] = e;
      if (lane == 0){ astore(&mS[(b*8+k)*2 + 0], m); astore(&mS[(b*8+k)*2 + 1], ssum); }
    }
    __syncthreads();

    // A3: V_k[c] = sum_{p in slice} e_p * feats[p][c]; stage in LDS, 16B store
    {
      float acc = 0.f;
      #pragma unroll 4
      for (int pl=0; pl<np; pl++) acc = fmaf(es[pl], b2f(ft_s[pl][tid]), acc);
      hks[tid] = acc;
    }
    __syncthreads();
    if (tid < 128) ic_store4(&Vpart[((size_t)(b*8+k))*FEATC + tid*4],
                             *reinterpret_cast<f32x4*>(&hks[tid*4]));

    // A4: gate partial over emb|h (768 cols) — overlaps store drain + barrier skew
    float a0=0.f,a1=0.f,a2=0.f,a3=0.f;
    gacc(wrow + s1, xs + s1, 256, a0,a1,a2,a3);
    gacc(wrow + s2, xs + s2, 128, a0,a1,a2,a3);

    fbar(fl, k, (unsigned)(2*t+1));   // -------- barrier A --------

    // ================= Phase B =================
    // B0: batched coherent loads of Vpart + mS; combine -> ctx
    f32x4 vq[8];
    if (tid < 128){
      const float* vp = Vpart + (size_t)b*8*FEATC + tid*4;
      #pragma unroll
      for (int kk=0;kk<8;kk++) vq[kk] = ic_load4(vp + (size_t)kk*FEATC);
    }
    if (tid < 16) msl[tid] = aload(&mS[b*16 + tid]);
    ic_wait();
    __syncthreads();
    if (tid < 128){
      float m = fmaxf(fmaxf(fmaxf(msl[0],msl[2]),fmaxf(msl[4],msl[6])),
                      fmaxf(fmaxf(msl[8],msl[10]),fmaxf(msl[12],msl[14])));
      float w[8]; float Z = 0.f;
      #pragma unroll
      for (int kk=0;kk<8;kk++){
        w[kk] = fexp2((msl[2*kk]-m)*1.4426950408889634f);
        Z = fmaf(msl[2*kk+1], w[kk], Z);
      }
      const float inv = 1.0f/Z;
      f32x4 cv = {0.f,0.f,0.f,0.f};
      #pragma unroll
      for (int kk=0;kk<8;kk++){
        cv.x = fmaf(w[kk], vq[kk].x, cv.x); cv.y = fmaf(w[kk], vq[kk].y, cv.y);
        cv.z = fmaf(w[kk], vq[kk].z, cv.z); cv.w = fmaf(w[kk], vq[kk].w, cv.w);
      }
      cv *= inv;
      *reinterpret_cast<f32x4*>(&xs[EMBN + tid*4]) = cv;
    }
    __syncthreads();

    // B1: finish gates with ctx cols (256 per thread), fold halves
    gacc(wrow + s3, xs + s3, 256, a0,a1,a2,a3);
    {
      float acc = (a0+a1)+(a2+a3);
      acc += __shfl_xor(acc, 1, 64);
      if (half == 0) gs[r2] = acc + biasCat[rowg];
    }
    __syncthreads();

    // B2: cell update for my 64 j's (c in registers)
    if (tid < 64){
      const int j = k*64 + tid;
      float gi = gs[tid*4+0], gf = gs[tid*4+1], gg = gs[tid*4+2], go = gs[tid*4+3];
      float cn = fsig(gf)*creg + fsig(gi)*ftanhf(gg);
      float hn = fsig(go)*ftanhf(cn);
      creg = cn;
      hnew[tid] = hn;
      Hb[((size_t)b*TTN + t)*HIDN + j] = __float2bfloat16(hn);
    }
    __syncthreads();
    if (tid < 16) ic_store4(&hstate[(size_t)b*HIDN + k*64 + tid*4],
                            *reinterpret_cast<f32x4*>(&hnew[tid*4]));

    // B3: next step's hk partial over my h slice (WkT slice L2-resident)
    {
      const bf16* wp = WkT + (size_t)(k*64)*AFFN + tid;
      float acc = 0.f;
      #pragma unroll 8
      for (int j=0;j<64;j++) acc = fmaf(b2f(wp[(size_t)j*AFFN]), hnew[j], acc);
      hks[tid] = acc;
    }
    __syncthreads();
    if (tid < 128) ic_store4(&part[((size_t)(b*8+k))*AFFN + tid*4],
                             *reinterpret_cast<f32x4*>(&hks[tid*4]));

    fbar(fl, k, (unsigned)(2*t+2));   // -------- barrier B --------
  }
}

static inline int cvt_grid(int nquad){ int g = (nquad + 255)/256; return g > 1024 ? 1024 : g; }

extern "C" void kernel_launch(void* const* d_in, const int* in_sizes, int n_in,
                              void* d_out, int out_size, void* d_ws, size_t ws_size,
                              hipStream_t stream) {
  const int* captions = (const int*)d_in[1];
  char* ws = (char*)d_ws;

  // ---- workspace layout (bytes) ----
  bf16*  feats  = (bf16*) (ws + 0);           // [6272][512] bf16
  bf16*  kvB    = (bf16*) (ws + 6422528);     // [6272][512] bf16
  float* hstate = (float*)(ws + 12845056);    // [32][512] f32
  float* cstate = (float*)(ws + 12976128);    // [32][512] f32
  float* part   = (float*)(ws + 13041664);    // [32][8][512] f32
  float* Vpart  = (float*)(ws + 13565952);    // [32][8][512] f32
  float* mS     = (float*)(ws + 14090240);    // [32][8][2] f32
  unsigned* flags=(unsigned*)(ws + 14092416); // 32 groups x 32 uints (128B stride)
  bf16*  Hb     = (bf16*) (ws + 14096512);    // [32][60][512] bf16
  bf16*  cnnB   = (bf16*) (ws + 16062592);    // [32][512][196] bf16 (dead after transpose+init)
  bf16*  WcatB  = (bf16*) (ws + 16062592);    // [2048][1280] bf16 — ALIASES cnnB
  bf16*  tableB = (bf16*) (ws + 22485120);
  bf16*  WkB    = (bf16*) (ws + 27605120);
  bf16*  WkTB   = (bf16*) (ws + 28129408);
  bf16*  WvB    = (bf16*) (ws + 28653696);
  bf16*  WhB    = (bf16*) (ws + 29177984);
  bf16*  WcB    = (bf16*) (ws + 29702272);
  bf16*  WihB   = (bf16*) (ws + 30226560);
  bf16*  WhhB   = (bf16*) (ws + 33372288);
  bf16*  WfcB   = (bf16*) (ws + 35469440);
  bf16*  waB    = (bf16*) (ws + 45709440);
  bf16*  bhB    = (bf16*) (ws + 45710464);
  bf16*  bcB    = (bf16*) (ws + 45711488);
  bf16*  bihB   = (bf16*) (ws + 45712512);
  bf16*  bhhB   = (bf16*) (ws + 45716608);
  bf16*  bfcB   = (bf16*) (ws + 45720704);
  float* biasCat= (float*)(ws + 45740704);
  int*   flag   = (int*)  (ws + 45748896);
  if (ws_size < 45748912ull) return;

  // 1) dtype probe + flag reset (coherent)
  k_probe<<<1, 256, 0, stream>>>((const uint32_t*)d_in[5], flag, flags);

  // 2) canonicalize to bf16
  struct CvtJob { const void* src; bf16* dst; int n; };
  const CvtJob jobs[15] = {
    {d_in[0],  cnnB,   3211264}, {d_in[2],  WkB,  262144}, {d_in[3],  WvB,  262144},
    {d_in[4],  waB,    512},     {d_in[5],  tableB, 2560000},
    {d_in[6],  WhB,    262144},  {d_in[7],  bhB,  512},
    {d_in[8],  WcB,    262144},  {d_in[9],  bcB,  512},
    {d_in[10], WihB,   1572864}, {d_in[11], WhhB, 1048576},
    {d_in[12], bihB,   2048},    {d_in[13], bhhB, 2048},
    {d_in[14], WfcB,   5120000}, {d_in[15], bfcB, 10000},
  };
  for (int i = 0; i < 15; i++){
    int nq = jobs[i].n / 4;
    k_cvt<<<cvt_grid(nq), 256, 0, stream>>>(jobs[i].src, jobs[i].dst, nq, flag);
  }

  // 3) precompute (cnnB consumers run BEFORE k_wcat overwrites that region)
  k_transpose<<<dim3(16,7,32), 256, 0, stream>>>(cnnB, feats);
  k_init<<<32, 256, 0, stream>>>(cnnB, WhB, bhB, WcB, bcB, hstate, cstate);
  k_wkt<<<dim3(16,16), 256, 0, stream>>>(WkB, WkTB);
  k_wcat<<<256, 256, 0, stream>>>(WihB, WhhB, bihB, bhhB, WcatB, biasCat);
  k_hk0<<<256, 512, 0, stream>>>(WkTB, hstate, part);
  gemm_bt<2,false,false><<<dim3(8,98), 256, 0, stream>>>(feats, WvB, (const bf16*)nullptr,
                                                   (void*)kvB, 6272, 512, 512, (const int*)nullptr);

  // 4) the whole recurrence: ONE persistent kernel, flag barriers + 16B coherent exchange
  k_pers<<<256, 512, 0, stream>>>(kvB, feats, WkTB, WcatB, biasCat, waB, tableB,
                                  captions, hstate, cstate, part, Vpart, mS, Hb, flags);

  // 5) logits = Hb @ Wfc^T + bfc (nontemporal C stores: don't thrash L2)
  gemm_bt<1,true,true><<<dim3(157,30), 256, 0, stream>>>(Hb, WfcB, bfcB, d_out,
                                                    1920, 10000, 512, flag);
}

// Round 6
// 1557.439 us; speedup vs baseline: 3.1405x; 1.2216x over previous
//
#include <hip/hip_runtime.h>
#include <hip/hip_bf16.h>
#include <cstdint>
#include <cstddef>

#define VOCABN 10000
#define FEATC 512
#define EMBN 256
#define HIDN 512
#define AFFN 512
#define BB 32
#define TTN 60
#define PPN 196
#define GROWS 2048

using bf16 = __hip_bfloat16;

typedef __attribute__((ext_vector_type(8))) short short8;
typedef __attribute__((ext_vector_type(4))) float f32x4;

__device__ __forceinline__ float b2f(bf16 x){ return __bfloat162float(x); }
__device__ __forceinline__ float fexp2(float x){ return __builtin_amdgcn_exp2f(x); }
__device__ __forceinline__ float frcp(float x){ return __builtin_amdgcn_rcpf(x); }
__device__ __forceinline__ float fsig(float x){ return frcp(1.f + fexp2(-1.4426950408889634f*x)); }
__device__ __forceinline__ float ftanhf(float x){ return 1.f - 2.f*frcp(1.f + fexp2(2.8853900817779268f*x)); }

// relaxed agent-scope accessors (device-coherent, no cache-maintenance fences)
__device__ __forceinline__ float aload(const float* p){
  return __hip_atomic_load((float*)p, __ATOMIC_RELAXED, __HIP_MEMORY_SCOPE_AGENT);
}
__device__ __forceinline__ void astore(float* p, float v){
  __hip_atomic_store(p, v, __ATOMIC_RELAXED, __HIP_MEMORY_SCOPE_AGENT);
}
__device__ __forceinline__ void astoreu(unsigned* p, unsigned v){
  __hip_atomic_store(p, v, __ATOMIC_RELAXED, __HIP_MEMORY_SCOPE_AGENT);
}
__device__ __forceinline__ unsigned aloadu(const unsigned* p){
  return __hip_atomic_load((unsigned*)p, __ATOMIC_RELAXED, __HIP_MEMORY_SCOPE_AGENT);
}

// 16B coherence-point load/store (sc0 sc1), f32x4 binds to a VGPR quad
__device__ __forceinline__ f32x4 ic_load4(const float* p){
  f32x4 r;
  asm volatile("global_load_dwordx4 %0, %1, off sc0 sc1" : "=&v"(r) : "v"(p));
  return r;
}
__device__ __forceinline__ void ic_store4(float* p, f32x4 v){
  asm volatile("global_store_dwordx4 %0, %1, off sc0 sc1" :: "v"(p), "v"(v) : "memory");
}
__device__ __forceinline__ void ic_wait(){
  asm volatile("s_waitcnt vmcnt(0)" ::: "memory");
  __builtin_amdgcn_sched_barrier(0);
}

__device__ __forceinline__ void unpack8(uint4 u, float* f){
  f[0] = __uint_as_float(u.x << 16); f[1] = __uint_as_float(u.x & 0xffff0000u);
  f[2] = __uint_as_float(u.y << 16); f[3] = __uint_as_float(u.y & 0xffff0000u);
  f[4] = __uint_as_float(u.z << 16); f[5] = __uint_as_float(u.z & 0xffff0000u);
  f[6] = __uint_as_float(u.w << 16); f[7] = __uint_as_float(u.w & 0xffff0000u);
}

// ---------- dtype probe + zero barrier flags ----------
__global__ void __launch_bounds__(256) k_probe(const uint32_t* __restrict__ w, int* __restrict__ flag,
                                               unsigned* __restrict__ flags){
  __shared__ int s;
  if (threadIdx.x == 0) s = 0;
  __syncthreads();
  int hit = 0;
  for (int i = threadIdx.x; i < 32768; i += 256){
    uint32_t v = w[i];
    if (((v & 0x7F800000u) == 0x7F800000u) || ((v & 0x00007F80u) == 0x00007F80u)) hit = 1;
  }
  if (hit) atomicOr(&s, 1);
  for (int i = threadIdx.x; i < 1024; i += 256) astoreu(&flags[i], 0u);
  __syncthreads();
  if (threadIdx.x == 0) flag[0] = s;
}

// ---------- canonicalize to bf16 ----------
__global__ void __launch_bounds__(256) k_cvt(const void* __restrict__ src, bf16* __restrict__ dst,
                                             int nquad, const int* __restrict__ flag){
  bool f32 = flag[0] != 0;
  int stride = gridDim.x * 256;
  for (int i = blockIdx.x*256 + threadIdx.x; i < nquad; i += stride){
    if (f32){
      float4 v = reinterpret_cast<const float4*>(src)[i];
      bf16* d = dst + 4*(size_t)i;
      d[0] = __float2bfloat16(v.x); d[1] = __float2bfloat16(v.y);
      d[2] = __float2bfloat16(v.z); d[3] = __float2bfloat16(v.w);
    } else {
      reinterpret_cast<uint2*>(dst)[i] = reinterpret_cast<const uint2*>(src)[i];
    }
  }
}

// ---------- feats[b][p][c] = cnn[b][c][p] ----------
__global__ void __launch_bounds__(256) k_transpose(const bf16* __restrict__ cnn, bf16* __restrict__ feats){
  __shared__ bf16 tile[32][34];
  int ct = blockIdx.x, pt = blockIdx.y, b = blockIdx.z;
  int tid = threadIdx.x;
  int lc = tid >> 5, lp = tid & 31;
  int p = pt*32 + lp;
  #pragma unroll
  for (int i=0;i<4;i++){
    int cc = ct*32 + lc + i*8;
    bf16 v = __float2bfloat16(0.f);
    if (p < PPN) v = cnn[((size_t)b*FEATC + cc)*PPN + p];
    tile[lc + i*8][lp] = v;
  }
  __syncthreads();
  #pragma unroll
  for (int i=0;i<4;i++){
    int pp = pt*32 + lc + i*8;
    if (pp < PPN) feats[((size_t)b*PPN + pp)*FEATC + ct*32 + lp] = tile[lp][lc + i*8];
  }
}

// ---------- WkT = Wk^T ----------
__global__ void __launch_bounds__(256) k_wkt(const bf16* __restrict__ W, bf16* __restrict__ WT){
  __shared__ bf16 tile[32][33];
  const int c0 = blockIdx.x*32, r0 = blockIdx.y*32;
  const int lc = threadIdx.x >> 5, lp = threadIdx.x & 31;
  #pragma unroll
  for (int i=0;i<4;i++) tile[lc + i*8][lp] = W[(size_t)(r0 + lc + i*8)*HIDN + c0 + lp];
  __syncthreads();
  #pragma unroll
  for (int i=0;i<4;i++) WT[(size_t)(c0 + lc + i*8)*HIDN + r0 + lp] = tile[lp][lc + i*8];
}

// ---------- gate weight split: rows r' = j*4+gate ----------
// Weh[r'][0..768): [Wih[src][0:256] | Whh[src][0:512)]   (emb|h columns)
// Wctx[r'][0..512): Wih[src][256:768]                     (ctx columns, for G GEMM)
__global__ void __launch_bounds__(256) k_wcat2(const bf16* __restrict__ Wih, const bf16* __restrict__ Whh,
      const bf16* __restrict__ bih, const bf16* __restrict__ bhh,
      bf16* __restrict__ Weh, bf16* __restrict__ Wctx, float* __restrict__ biasCat){
  const int rloc = threadIdx.x >> 5, lane32 = threadIdx.x & 31;
  const int r = blockIdx.x*8 + rloc;
  const int j = r >> 2, g = r & 3;
  const int src = g*HIDN + j;
  for (int e4 = lane32; e4 < 192; e4 += 32){
    const int e = e4*4;
    uint2 v = (e < 256) ? *reinterpret_cast<const uint2*>(Wih + (size_t)src*768 + e)
                        : *reinterpret_cast<const uint2*>(Whh + (size_t)src*HIDN + (e - 256));
    *reinterpret_cast<uint2*>(Weh + (size_t)r*768 + e) = v;
  }
  for (int e4 = lane32; e4 < 128; e4 += 32){
    const int e = e4*4;
    *reinterpret_cast<uint2*>(Wctx + (size_t)r*512 + e) =
        *reinterpret_cast<const uint2*>(Wih + (size_t)src*768 + 256 + e);
  }
  if (lane32 == 0) biasCat[r] = b2f(bih[src]) + b2f(bhh[src]);
}

// ---------- g = mean_p cnn ; h0, c0 (published coherently) ----------
__global__ void __launch_bounds__(256) k_init(const bf16* __restrict__ cnn,
      const bf16* __restrict__ Wh, const bf16* __restrict__ bh,
      const bf16* __restrict__ Wc, const bf16* __restrict__ bc,
      float* __restrict__ h, float* __restrict__ c){
  __shared__ float gl[FEATC];
  int b = blockIdx.x, tid = threadIdx.x;
  for (int cc = tid; cc < FEATC; cc += 256){
    const bf16* src = cnn + ((size_t)b*FEATC + cc)*PPN;
    const uint2* sp = reinterpret_cast<const uint2*>(src);
    float acc = 0.f;
    for (int q=0;q<PPN/4;q++){
      uint2 u = sp[q];
      acc += __uint_as_float(u.x<<16) + __uint_as_float(u.x&0xffff0000u)
           + __uint_as_float(u.y<<16) + __uint_as_float(u.y&0xffff0000u);
    }
    gl[cc] = acc * (1.0f/196.0f);
  }
  __syncthreads();
  for (int i = tid; i < HIDN; i += 256){
    const uint4* wr1 = reinterpret_cast<const uint4*>(Wh + (size_t)i*FEATC);
    const uint4* wr2 = reinterpret_cast<const uint4*>(Wc + (size_t)i*FEATC);
    float a1 = 0.f, a2 = 0.f;
    #pragma unroll 4
    for (int k8=0; k8<FEATC/8; k8++){
      float w1[8], w2[8];
      unpack8(wr1[k8], w1); unpack8(wr2[k8], w2);
      const float* gp = &gl[k8*8];
      #pragma unroll
      for (int j=0;j<8;j++){ a1 = fmaf(w1[j], gp[j], a1); a2 = fmaf(w2[j], gp[j], a2); }
    }
    astore(&h[b*HIDN+i], a1 + b2f(bh[i]));
    astore(&c[b*HIDN+i], a2 + b2f(bc[i]));
  }
}

// ---------- initial hk partials from h0 ----------
__global__ void __launch_bounds__(512) k_hk0(const bf16* __restrict__ WkT,
      const float* __restrict__ h, float* __restrict__ part){
  __shared__ float hl[64];
  const int tid = threadIdx.x;
  const int k = blockIdx.x & 7, b = blockIdx.x >> 3;
  if (tid < 64) hl[tid] = aload(&h[b*HIDN + k*64 + tid]);
  __syncthreads();
  const bf16* wp = WkT + (size_t)(k*64)*AFFN + tid;
  float acc = 0.f;
  #pragma unroll 8
  for (int j=0; j<64; j++) acc = fmaf(b2f(wp[(size_t)j*AFFN]), hl[j], acc);
  astore(&part[((size_t)(b*8 + k))*AFFN + tid], acc);
}

// ---------- generic MFMA GEMM: C[M][N] = A[M][K] @ Bw[N][K]^T (+bias) ----------
template<int OUTMODE, bool BIAS, bool NT>
__global__ void __launch_bounds__(256) gemm_bt(const bf16* __restrict__ A, const bf16* __restrict__ Bw,
        const bf16* __restrict__ bias, void* __restrict__ Cout, int M, int N, int K,
        const int* __restrict__ flag){
  __shared__ __align__(16) bf16 As[64][40];
  __shared__ __align__(16) bf16 Bs[64][40];
  int tid = threadIdx.x;
  int m0 = blockIdx.y*64, n0 = blockIdx.x*64;
  int lr = tid >> 2;
  int lk = (tid & 3)*8;
  int wave = tid >> 6, lane = tid & 63;
  int ml = lane & 15, kg = lane >> 4;
  f32x4 acc0 = {0.f,0.f,0.f,0.f}, acc1 = acc0, acc2 = acc0, acc3 = acc0;
  for (int k0=0; k0<K; k0+=32){
    __syncthreads();
    {
      uint4 av = *reinterpret_cast<const uint4*>(A + (size_t)(m0+lr)*K + k0 + lk);
      *reinterpret_cast<uint4*>(&As[lr][lk]) = av;
      uint4 bv = make_uint4(0u,0u,0u,0u);
      int bn = n0 + lr;
      if (bn < N) bv = *reinterpret_cast<const uint4*>(Bw + (size_t)bn*K + k0 + lk);
      *reinterpret_cast<uint4*>(&Bs[lr][lk]) = bv;
    }
    __syncthreads();
    short8 af = *reinterpret_cast<const short8*>(&As[wave*16 + ml][kg*8]);
    short8 b0 = *reinterpret_cast<const short8*>(&Bs[ 0 + ml][kg*8]);
    short8 b1 = *reinterpret_cast<const short8*>(&Bs[16 + ml][kg*8]);
    short8 b2 = *reinterpret_cast<const short8*>(&Bs[32 + ml][kg*8]);
    short8 b3 = *reinterpret_cast<const short8*>(&Bs[48 + ml][kg*8]);
    acc0 = __builtin_amdgcn_mfma_f32_16x16x32_bf16(af, b0, acc0, 0,0,0);
    acc1 = __builtin_amdgcn_mfma_f32_16x16x32_bf16(af, b1, acc1, 0,0,0);
    acc2 = __builtin_amdgcn_mfma_f32_16x16x32_bf16(af, b2, acc2, 0,0,0);
    acc3 = __builtin_amdgcn_mfma_f32_16x16x32_bf16(af, b3, acc3, 0,0,0);
  }
  bool of32;
  if (OUTMODE == 0) of32 = true;
  else if (OUTMODE == 2) of32 = false;
  else of32 = (flag[0] != 0);
  int mb = m0 + wave*16 + (lane>>4)*4;
  int cl = lane & 15;
  f32x4 av[4] = {acc0, acc1, acc2, acc3};
  #pragma unroll
  for (int j=0;j<4;j++){
    int n = n0 + j*16 + cl;
    if (n < N){
      float bv = BIAS ? b2f(bias[n]) : 0.f;
      #pragma unroll
      for (int rr=0; rr<4; rr++){
        float v = av[j][rr] + bv;
        if (of32){
          float* p = &((float*)Cout)[(size_t)(mb+rr)*N + n];
          if (NT) __builtin_nontemporal_store(v, p); else *p = v;
        } else {
          bf16 hv = __float2bfloat16(v);
          short sv = *reinterpret_cast<short*>(&hv);
          short* p = reinterpret_cast<short*>(&((bf16*)Cout)[(size_t)(mb+rr)*N + n]);
          if (NT) __builtin_nontemporal_store(sv, p); else *p = sv;
        }
      }
    }
  }
}

// ---------- G precompute: G_b[2048][196] = Wctx[2048][512] @ feats_b[196][512]^T ----------
__global__ void __launch_bounds__(256) gemm_gb(const bf16* __restrict__ A, const bf16* __restrict__ BwAll,
        bf16* __restrict__ Gout){
  const bf16* Bw = BwAll + (size_t)blockIdx.z*PPN*FEATC;
  bf16* Cout = Gout + (size_t)blockIdx.z*GROWS*PPN;
  __shared__ __align__(16) bf16 As[64][40];
  __shared__ __align__(16) bf16 Bs[64][40];
  int tid = threadIdx.x;
  int m0 = blockIdx.y*64, n0 = blockIdx.x*64;
  int lr = tid >> 2;
  int lk = (tid & 3)*8;
  int wave = tid >> 6, lane = tid & 63;
  int ml = lane & 15, kg = lane >> 4;
  f32x4 acc0 = {0.f,0.f,0.f,0.f}, acc1 = acc0, acc2 = acc0, acc3 = acc0;
  for (int k0=0; k0<FEATC; k0+=32){
    __syncthreads();
    {
      uint4 av = *reinterpret_cast<const uint4*>(A + (size_t)(m0+lr)*FEATC + k0 + lk);
      *reinterpret_cast<uint4*>(&As[lr][lk]) = av;
      uint4 bv = make_uint4(0u,0u,0u,0u);
      int bn = n0 + lr;
      if (bn < PPN) bv = *reinterpret_cast<const uint4*>(Bw + (size_t)bn*FEATC + k0 + lk);
      *reinterpret_cast<uint4*>(&Bs[lr][lk]) = bv;
    }
    __syncthreads();
    short8 af = *reinterpret_cast<const short8*>(&As[wave*16 + ml][kg*8]);
    short8 b0 = *reinterpret_cast<const short8*>(&Bs[ 0 + ml][kg*8]);
    short8 b1 = *reinterpret_cast<const short8*>(&Bs[16 + ml][kg*8]);
    short8 b2 = *reinterpret_cast<const short8*>(&Bs[32 + ml][kg*8]);
    short8 b3 = *reinterpret_cast<const short8*>(&Bs[48 + ml][kg*8]);
    acc0 = __builtin_amdgcn_mfma_f32_16x16x32_bf16(af, b0, acc0, 0,0,0);
    acc1 = __builtin_amdgcn_mfma_f32_16x16x32_bf16(af, b1, acc1, 0,0,0);
    acc2 = __builtin_amdgcn_mfma_f32_16x16x32_bf16(af, b2, acc2, 0,0,0);
    acc3 = __builtin_amdgcn_mfma_f32_16x16x32_bf16(af, b3, acc3, 0,0,0);
  }
  int mb = m0 + wave*16 + (lane>>4)*4;
  int cl = lane & 15;
  f32x4 av[4] = {acc0, acc1, acc2, acc3};
  #pragma unroll
  for (int j=0;j<4;j++){
    int n = n0 + j*16 + cl;
    if (n < PPN){
      #pragma unroll
      for (int rr=0; rr<4; rr++)
        Cout[(size_t)(mb+rr)*PPN + n] = __float2bfloat16(av[j][rr]);
    }
  }
}

// ---------- split flag barrier: signal early, wait late ----------
__device__ __forceinline__ void fbar_signal(unsigned* f8, int myk, unsigned token){
  asm volatile("s_waitcnt vmcnt(0)" ::: "memory");
  __syncthreads();
  if (threadIdx.x == 0) astoreu(&f8[myk], token);
}
__device__ __forceinline__ void fbar_wait(unsigned* f8, unsigned token){
  const int lane = threadIdx.x & 63;
  unsigned guard = 0;
  for (;;){
    unsigned v = (lane < 8) ? aloadu(&f8[lane]) : token;
    if (__all((int)(v >= token))) break;
    if (++guard > 50000000u) break;
    __builtin_amdgcn_s_sleep(1);
  }
  __syncthreads();
}

// gate partial accumulator
__device__ __forceinline__ void gacc(const bf16* w, const float* x, int len,
                                     float& a0, float& a1, float& a2, float& a3){
  #pragma unroll 4
  for (int e=0; e<len; e+=8){
    float w8[8]; unpack8(*reinterpret_cast<const uint4*>(w+e), w8);
    float4 x0 = *reinterpret_cast<const float4*>(x+e);
    float4 x1 = *reinterpret_cast<const float4*>(x+e+4);
    a0 = fmaf(w8[0],x0.x,a0); a1 = fmaf(w8[1],x0.y,a1);
    a2 = fmaf(w8[2],x0.z,a2); a3 = fmaf(w8[3],x0.w,a3);
    a0 = fmaf(w8[4],x1.x,a0); a1 = fmaf(w8[5],x1.y,a1);
    a2 = fmaf(w8[6],x1.z,a2); a3 = fmaf(w8[7],x1.w,a3);
  }
}

// ---------- persistent recurrence, G-trick, 2 light barriers/step ----------
// block (b,k): b=bid>>3, k=bid&7. LDS: kv p-slice (25 rows) + G row-slice (256 rows x 196).
// ctx never materializes: gate = eh-partial(emb|h) + sum_p alpha_p * G[row][p] + bias.
__global__ void __launch_bounds__(512) k_pers(
    const bf16* __restrict__ kvB, const bf16* __restrict__ WkT,
    const bf16* __restrict__ Weh, const bf16* __restrict__ Gglob,
    const float* __restrict__ biasCat, const bf16* __restrict__ wa,
    const bf16* __restrict__ table, const int* __restrict__ captions,
    float* __restrict__ hstate, const float* __restrict__ cinit,
    float* __restrict__ part,            // [32][8][512]
    float* __restrict__ zarr,            // [32][8][32]
    bf16* __restrict__ Hb, unsigned* __restrict__ flags)
{
  extern __shared__ __align__(16) char dynsm[];
  bf16* kv_s = reinterpret_cast<bf16*>(dynsm);            // [25][512]
  bf16* G_s  = reinterpret_cast<bf16*>(dynsm + 25600);    // [256][196]
  __shared__ __align__(16) float xs[768];    // emb[0,256) | h[256,768)
  __shared__ __align__(16) float hks[512];   // hk; reused as part' staging
  __shared__ __align__(16) float als[200];   // z -> alpha
  __shared__ __align__(16) float gs[256];
  __shared__ __align__(16) float zes[32];
  __shared__ __align__(16) float hnew[64];

  const int tid = threadIdx.x;
  const int bid = blockIdx.x;
  const int k = bid & 7, b = bid >> 3;
  unsigned* fl = flags + b*32;
  const int np = (k < 4) ? 25 : 24;
  const int p0 = (k < 4) ? k*25 : 100 + (k-4)*24;
  const int lane = tid & 63, wv = tid >> 6;

  const int r2 = tid >> 1, half = tid & 1;
  const int rowg = k*256 + r2;

  // ---- prologue: stage kv p-slice + G row-slice into LDS (once) ----
  {
    const uint4* src = reinterpret_cast<const uint4*>(kvB + ((size_t)(b*PPN + p0))*AFFN);
    uint4* dst = reinterpret_cast<uint4*>(kv_s);
    for (int i = tid; i < np*64; i += 512) dst[i] = src[i];
  }
  {
    const uint2* src = reinterpret_cast<const uint2*>(Gglob + ((size_t)(b*GROWS) + k*256)*PPN);
    uint2* dst = reinterpret_cast<uint2*>(G_s);
    for (int i = tid; i < 12544; i += 512) dst[i] = src[i];   // 256*196*2B / 8
  }
  float creg = 0.f;
  if (tid < 64) creg = cinit[b*HIDN + k*64 + tid];
  float wf[8];
  unpack8(*reinterpret_cast<const uint4*>(wa + lane*8), wf);
  __syncthreads();

  for (int t = 0; t < TTN; t++){
    // ---- A0: hk partials (tid<128), h (128..255), emb (256..511)
    f32x4 pq[8]; f32x4 hq;
    if (tid < 128){
      const float* pp = part + (size_t)b*8*AFFN + tid*4;
      #pragma unroll
      for (int kk=0;kk<8;kk++) pq[kk] = ic_load4(pp + (size_t)kk*AFFN);
    } else if (tid < 256){
      hq = ic_load4(hstate + (size_t)b*HIDN + (tid-128)*4);
    } else {
      const int tok = captions[b*TTN + t];
      xs[tid-256] = b2f(table[(size_t)tok*EMBN + (tid-256)]);
    }
    ic_wait();
    if (tid < 128){
      f32x4 s = pq[0];
      #pragma unroll
      for (int kk=1;kk<8;kk++) s += pq[kk];
      *reinterpret_cast<f32x4*>(&hks[tid*4]) = s;
    } else if (tid < 256){
      *reinterpret_cast<f32x4*>(&xs[256 + (tid-128)*4]) = hq;
    }
    __syncthreads();

    // ---- z for my p-slice (wave per p)
    {
      float hf[8];
      const float4* hp = reinterpret_cast<const float4*>(&hks[lane*8]);
      float4 t0 = hp[0], t1 = hp[1];
      hf[0]=t0.x; hf[1]=t0.y; hf[2]=t0.z; hf[3]=t0.w;
      hf[4]=t1.x; hf[5]=t1.y; hf[6]=t1.z; hf[7]=t1.w;
      for (int pl = wv; pl < np; pl += 8){
        float kf[8]; unpack8(*reinterpret_cast<const uint4*>(kv_s + pl*512 + lane*8), kf);
        float acc = wf[0]*ftanhf(kf[0]+hf[0]) + wf[1]*ftanhf(kf[1]+hf[1])
                  + wf[2]*ftanhf(kf[2]+hf[2]) + wf[3]*ftanhf(kf[3]+hf[3])
                  + wf[4]*ftanhf(kf[4]+hf[4]) + wf[5]*ftanhf(kf[5]+hf[5])
                  + wf[6]*ftanhf(kf[6]+hf[6]) + wf[7]*ftanhf(kf[7]+hf[7]);
        #pragma unroll
        for (int s=1;s<64;s<<=1) acc += __shfl_xor(acc, s, 64);
        if (lane == 0) zes[pl] = acc;
      }
    }
    __syncthreads();
    if (tid < 8) ic_store4(&zarr[(size_t)(b*8+k)*32 + tid*4],
                           *reinterpret_cast<f32x4*>(&zes[tid*4]));

    fbar_signal(fl, k, (unsigned)(2*t+1));   // signal EARLY

    // ---- eh gate partial (768 cols) — runs while others arrive
    float a0=0.f,a1=0.f,a2=0.f,a3=0.f;
    gacc(Weh + (size_t)rowg*768 + half*384, xs + half*384, 384, a0,a1,a2,a3);

    fbar_wait(fl, (unsigned)(2*t+1));        // barrier A done

    // ---- gather z, local full softmax
    f32x4 zq;
    if (tid < 64) zq = ic_load4(&zarr[(size_t)b*256 + tid*4]);
    ic_wait();
    if (tid < 64){
      const int kk2 = tid >> 3, i0 = (tid & 7)*4;
      const int npk = (kk2 < 4) ? 25 : 24;
      const int p0k = (kk2 < 4) ? kk2*25 : 100 + (kk2-4)*24;
      #pragma unroll
      for (int jj=0;jj<4;jj++) if (i0+jj < npk) als[p0k+i0+jj] = zq[jj];
    }
    __syncthreads();
    if (wv == 0){
      float m = -1e30f;
      for (int i=lane;i<PPN;i+=64) m = fmaxf(m, als[i]);
      #pragma unroll
      for (int s=1;s<64;s<<=1) m = fmaxf(m, __shfl_xor(m, s, 64));
      float ssum = 0.f;
      for (int i=lane;i<PPN;i+=64){
        float e = fexp2((als[i]-m)*1.4426950408889634f);
        als[i] = e; ssum += e;
      }
      #pragma unroll
      for (int s=1;s<64;s<<=1) ssum += __shfl_xor(ssum, s, 64);
      float inv = 1.0f/ssum;
      for (int i=lane;i<PPN;i+=64) als[i] *= inv;
    }
    __syncthreads();

    // ---- ctx contribution via G (98 LDS MACs / thread)
    float ga = 0.f;
    {
      const uint32_t* gr = reinterpret_cast<const uint32_t*>(G_s + r2*PPN + half*98);
      const float* ap = als + half*98;
      #pragma unroll 7
      for (int i=0;i<49;i++){
        uint32_t u = gr[i];
        ga = fmaf(__uint_as_float(u << 16),          ap[2*i],   ga);
        ga = fmaf(__uint_as_float(u & 0xffff0000u),  ap[2*i+1], ga);
      }
    }
    {
      float acc = (a0+a1)+(a2+a3) + ga;
      acc += __shfl_xor(acc, 1, 64);
      if (half == 0) gs[r2] = acc + biasCat[rowg];
    }
    __syncthreads();

    // ---- cell update (c in registers)
    if (tid < 64){
      const int j = k*64 + tid;
      float gi = gs[tid*4+0], gf = gs[tid*4+1], gg = gs[tid*4+2], go = gs[tid*4+3];
      float cn = fsig(gf)*creg + fsig(gi)*ftanhf(gg);
      float hn = fsig(go)*ftanhf(cn);
      creg = cn;
      hnew[tid] = hn;
      Hb[((size_t)b*TTN + t)*HIDN + j] = __float2bfloat16(hn);
    }
    __syncthreads();
    if (tid < 16) ic_store4(&hstate[(size_t)b*HIDN + k*64 + tid*4],
                            *reinterpret_cast<f32x4*>(&hnew[tid*4]));

    // ---- next step's hk partial over my h slice
    {
      const bf16* wp = WkT + (size_t)(k*64)*AFFN + tid;
      float acc = 0.f;
      #pragma unroll 8
      for (int j=0;j<64;j++) acc = fmaf(b2f(wp[(size_t)j*AFFN]), hnew[j], acc);
      hks[tid] = acc;
    }
    __syncthreads();
    if (tid < 128) ic_store4(&part[((size_t)(b*8+k))*AFFN + tid*4],
                             *reinterpret_cast<f32x4*>(&hks[tid*4]));

    fbar_signal(fl, k, (unsigned)(2*t+2));
    fbar_wait(fl, (unsigned)(2*t+2));        // barrier B
  }
}

static inline int cvt_grid(int nquad){ int g = (nquad + 255)/256; return g > 1024 ? 1024 : g; }

extern "C" void kernel_launch(void* const* d_in, const int* in_sizes, int n_in,
                              void* d_out, int out_size, void* d_ws, size_t ws_size,
                              hipStream_t stream) {
  const int* captions = (const int*)d_in[1];
  char* ws = (char*)d_ws;

  // ---- workspace layout (bytes) ----
  bf16*  feats  = (bf16*) (ws + 0);           // [6272][512] bf16
  bf16*  kvB    = (bf16*) (ws + 6422528);     // [6272][512] bf16
  float* hstate = (float*)(ws + 12845056);    // [32][512] f32
  float* cstate = (float*)(ws + 12910592);    // [32][512] f32
  float* part   = (float*)(ws + 12976128);    // [32][8][512] f32
  float* zarr   = (float*)(ws + 13500416);    // [32][8][32] f32
  unsigned* flags=(unsigned*)(ws + 13533184); // 32 groups x 32 uints
  bf16*  Hb     = (bf16*) (ws + 13537280);    // [32][60][512] bf16
  bf16*  cnnB   = (bf16*) (ws + 15503360);    // [32][512][196] bf16 (dead after transpose+init)
  bf16*  WehB   = (bf16*) (ws + 15503360);    // [2048][768] — ALIASES cnnB
  bf16*  WctxB  = (bf16*) (ws + 18649088);    // [2048][512] — ALIASES cnnB
  bf16*  tableB = (bf16*) (ws + 21925888);
  bf16*  WkB    = (bf16*) (ws + 27045888);
  bf16*  WkTB   = (bf16*) (ws + 27570176);
  bf16*  WvB    = (bf16*) (ws + 28094464);
  bf16*  WhB    = (bf16*) (ws + 28618752);
  bf16*  WcB    = (bf16*) (ws + 29143040);
  bf16*  WihB   = (bf16*) (ws + 29667328);
  bf16*  WhhB   = (bf16*) (ws + 32813056);
  bf16*  WfcB   = (bf16*) (ws + 34910208);
  bf16*  waB    = (bf16*) (ws + 45150208);
  bf16*  bhB    = (bf16*) (ws + 45151232);
  bf16*  bcB    = (bf16*) (ws + 45152256);
  bf16*  bihB   = (bf16*) (ws + 45153280);
  bf16*  bhhB   = (bf16*) (ws + 45157376);
  bf16*  bfcB   = (bf16*) (ws + 45161472);
  float* biasCat= (float*)(ws + 45181472);
  int*   flag   = (int*)  (ws + 45189664);
  if (ws_size < 45189680ull) return;

  // G (step-invariant ctx-gate matrix) lives in d_out as scratch: 25.7MB << out_size
  bf16* Gglob = (bf16*)d_out;

  // 1) dtype probe + flag reset
  k_probe<<<1, 256, 0, stream>>>((const uint32_t*)d_in[5], flag, flags);

  // 2) canonicalize to bf16
  struct CvtJob { const void* src; bf16* dst; int n; };
  const CvtJob jobs[15] = {
    {d_in[0],  cnnB,   3211264}, {d_in[2],  WkB,  262144}, {d_in[3],  WvB,  262144},
    {d_in[4],  waB,    512},     {d_in[5],  tableB, 2560000},
    {d_in[6],  WhB,    262144},  {d_in[7],  bhB,  512},
    {d_in[8],  WcB,    262144},  {d_in[9],  bcB,  512},
    {d_in[10], WihB,   1572864}, {d_in[11], WhhB, 1048576},
    {d_in[12], bihB,   2048},    {d_in[13], bhhB, 2048},
    {d_in[14], WfcB,   5120000}, {d_in[15], bfcB, 10000},
  };
  for (int i = 0; i < 15; i++){
    int nq = jobs[i].n / 4;
    k_cvt<<<cvt_grid(nq), 256, 0, stream>>>(jobs[i].src, jobs[i].dst, nq, flag);
  }

  // 3) precompute (cnnB consumers BEFORE k_wcat2 overwrites the region)
  k_transpose<<<dim3(16,7,32), 256, 0, stream>>>(cnnB, feats);
  k_init<<<32, 256, 0, stream>>>(cnnB, WhB, bhB, WcB, bcB, hstate, cstate);
  k_wkt<<<dim3(16,16), 256, 0, stream>>>(WkB, WkTB);
  k_wcat2<<<256, 256, 0, stream>>>(WihB, WhhB, bihB, bhhB, WehB, WctxB, biasCat);
  k_hk0<<<256, 512, 0, stream>>>(WkTB, hstate, part);
  gemm_bt<2,false,false><<<dim3(8,98), 256, 0, stream>>>(feats, WvB, (const bf16*)nullptr,
                                                   (void*)kvB, 6272, 512, 512, (const int*)nullptr);
  gemm_gb<<<dim3(4,32,32), 256, 0, stream>>>(WctxB, feats, Gglob);

  // 4) the whole recurrence: ONE persistent kernel (dyn LDS: kv 25KB + G 100KB)
  k_pers<<<256, 512, 125952, stream>>>(kvB, WkTB, WehB, Gglob, biasCat, waB, tableB,
                                       captions, hstate, cstate, part, zarr, Hb, flags);

  // 5) logits = Hb @ Wfc^T + bfc (overwrites the G scratch region of d_out)
  gemm_bt<1,true,true><<<dim3(157,30), 256, 0, stream>>>(Hb, WfcB, bfcB, d_out,
                                                    1920, 10000, 512, flag);
}

// Round 7
// 1344.412 us; speedup vs baseline: 3.6381x; 1.1585x over previous
//
#include <hip/hip_runtime.h>
#include <hip/hip_bf16.h>
#include <cstdint>
#include <cstddef>

#define VOCABN 10000
#define FEATC 512
#define EMBN 256
#define HIDN 512
#define AFFN 512
#define BB 32
#define TTN 60
#define PPN 196
#define GROWS 2048

using bf16 = __hip_bfloat16;

typedef __attribute__((ext_vector_type(8))) short short8;
typedef __attribute__((ext_vector_type(4))) float f32x4;

__device__ __forceinline__ float b2f(bf16 x){ return __bfloat162float(x); }
__device__ __forceinline__ float fexp2(float x){ return __builtin_amdgcn_exp2f(x); }
__device__ __forceinline__ float frcp(float x){ return __builtin_amdgcn_rcpf(x); }
__device__ __forceinline__ float fsig(float x){ return frcp(1.f + fexp2(-1.4426950408889634f*x)); }
__device__ __forceinline__ float ftanhf(float x){ return 1.f - 2.f*frcp(1.f + fexp2(2.8853900817779268f*x)); }

// relaxed agent-scope accessors (device-coherent, no cache-maintenance fences)
__device__ __forceinline__ void astore(float* p, float v){
  __hip_atomic_store(p, v, __ATOMIC_RELAXED, __HIP_MEMORY_SCOPE_AGENT);
}
__device__ __forceinline__ void astoreu(unsigned* p, unsigned v){
  __hip_atomic_store(p, v, __ATOMIC_RELAXED, __HIP_MEMORY_SCOPE_AGENT);
}
__device__ __forceinline__ unsigned aloadu(const unsigned* p){
  return __hip_atomic_load((unsigned*)p, __ATOMIC_RELAXED, __HIP_MEMORY_SCOPE_AGENT);
}
__device__ __forceinline__ float aload(const float* p){
  return __hip_atomic_load((float*)p, __ATOMIC_RELAXED, __HIP_MEMORY_SCOPE_AGENT);
}

// 16B coherence-point load/store (sc0 sc1); f32x4 binds to a VGPR quad
__device__ __forceinline__ f32x4 ic_load4(const float* p){
  f32x4 r;
  asm volatile("global_load_dwordx4 %0, %1, off sc0 sc1" : "=&v"(r) : "v"(p));
  return r;
}
__device__ __forceinline__ void ic_store4(float* p, f32x4 v){
  asm volatile("global_store_dwordx4 %0, %1, off sc0 sc1" :: "v"(p), "v"(v) : "memory");
}
__device__ __forceinline__ void ic_wait(){
  asm volatile("s_waitcnt vmcnt(0)" ::: "memory");
  __builtin_amdgcn_sched_barrier(0);
}

__device__ __forceinline__ void unpack8(uint4 u, float* f){
  f[0] = __uint_as_float(u.x << 16); f[1] = __uint_as_float(u.x & 0xffff0000u);
  f[2] = __uint_as_float(u.y << 16); f[3] = __uint_as_float(u.y & 0xffff0000u);
  f[4] = __uint_as_float(u.z << 16); f[5] = __uint_as_float(u.z & 0xffff0000u);
  f[6] = __uint_as_float(u.w << 16); f[7] = __uint_as_float(u.w & 0xffff0000u);
}

// ---------- dtype probe + zero barrier flags ----------
__global__ void __launch_bounds__(256) k_probe(const uint32_t* __restrict__ w, int* __restrict__ flag,
                                               unsigned* __restrict__ flags){
  __shared__ int s;
  if (threadIdx.x == 0) s = 0;
  __syncthreads();
  int hit = 0;
  for (int i = threadIdx.x; i < 32768; i += 256){
    uint32_t v = w[i];
    if (((v & 0x7F800000u) == 0x7F800000u) || ((v & 0x00007F80u) == 0x00007F80u)) hit = 1;
  }
  if (hit) atomicOr(&s, 1);
  for (int i = threadIdx.x; i < 1024; i += 256) astoreu(&flags[i], 0u);
  __syncthreads();
  if (threadIdx.x == 0) flag[0] = s;
}

// ---------- batched canonicalize: 14 tensors in one launch ----------
struct CvtJobs { const void* src[14]; void* dst[14]; int nq[14]; };
__global__ void __launch_bounds__(256) k_cvtall(CvtJobs J, const int* __restrict__ flag){
  bool f32 = flag[0] != 0;
  const int job = blockIdx.y;
  const int nq = J.nq[job];
  const void* src = J.src[job];
  bf16* dst = (bf16*)J.dst[job];
  for (int i = blockIdx.x*256 + threadIdx.x; i < nq; i += 256*256){
    if (f32){
      float4 v = reinterpret_cast<const float4*>(src)[i];
      bf16* d = dst + 4*(size_t)i;
      d[0] = __float2bfloat16(v.x); d[1] = __float2bfloat16(v.y);
      d[2] = __float2bfloat16(v.z); d[3] = __float2bfloat16(v.w);
    } else {
      reinterpret_cast<uint2*>(dst)[i] = reinterpret_cast<const uint2*>(src)[i];
    }
  }
}

// ---------- single-tensor cvt (for WfcB, after k_pers) ----------
__global__ void __launch_bounds__(256) k_cvt(const void* __restrict__ src, bf16* __restrict__ dst,
                                             int nquad, const int* __restrict__ flag){
  bool f32 = flag[0] != 0;
  int stride = gridDim.x * 256;
  for (int i = blockIdx.x*256 + threadIdx.x; i < nquad; i += stride){
    if (f32){
      float4 v = reinterpret_cast<const float4*>(src)[i];
      bf16* d = dst + 4*(size_t)i;
      d[0] = __float2bfloat16(v.x); d[1] = __float2bfloat16(v.y);
      d[2] = __float2bfloat16(v.z); d[3] = __float2bfloat16(v.w);
    } else {
      reinterpret_cast<uint2*>(dst)[i] = reinterpret_cast<const uint2*>(src)[i];
    }
  }
}

// ---------- feats[b][p][c] = cnn[b][c][p] ----------
__global__ void __launch_bounds__(256) k_transpose(const bf16* __restrict__ cnn, bf16* __restrict__ feats){
  __shared__ bf16 tile[32][34];
  int ct = blockIdx.x, pt = blockIdx.y, b = blockIdx.z;
  int tid = threadIdx.x;
  int lc = tid >> 5, lp = tid & 31;
  int p = pt*32 + lp;
  #pragma unroll
  for (int i=0;i<4;i++){
    int cc = ct*32 + lc + i*8;
    bf16 v = __float2bfloat16(0.f);
    if (p < PPN) v = cnn[((size_t)b*FEATC + cc)*PPN + p];
    tile[lc + i*8][lp] = v;
  }
  __syncthreads();
  #pragma unroll
  for (int i=0;i<4;i++){
    int pp = pt*32 + lc + i*8;
    if (pp < PPN) feats[((size_t)b*PPN + pp)*FEATC + ct*32 + lp] = tile[lp][lc + i*8];
  }
}

// ---------- WkT = Wk^T ----------
__global__ void __launch_bounds__(256) k_wkt(const bf16* __restrict__ W, bf16* __restrict__ WT){
  __shared__ bf16 tile[32][33];
  const int c0 = blockIdx.x*32, r0 = blockIdx.y*32;
  const int lc = threadIdx.x >> 5, lp = threadIdx.x & 31;
  #pragma unroll
  for (int i=0;i<4;i++) tile[lc + i*8][lp] = W[(size_t)(r0 + lc + i*8)*HIDN + c0 + lp];
  __syncthreads();
  #pragma unroll
  for (int i=0;i<4;i++) WT[(size_t)(c0 + lc + i*8)*HIDN + r0 + lp] = tile[lp][lc + i*8];
}

// ---------- gate weight split, rows r' = j*4+gate ----------
// Whc[r'][512) = Whh[src][:]; Wemb[r'][256) = Wih[src][0:256); Wctx[r'][512) = Wih[src][256:768)
__global__ void __launch_bounds__(256) k_wcat3(const bf16* __restrict__ Wih, const bf16* __restrict__ Whh,
      const bf16* __restrict__ bih, const bf16* __restrict__ bhh,
      bf16* __restrict__ Whc, bf16* __restrict__ Wemb, bf16* __restrict__ Wctx,
      bf16* __restrict__ biasCatB){
  const int rloc = threadIdx.x >> 5, lane32 = threadIdx.x & 31;
  const int r = blockIdx.x*8 + rloc;
  const int j = r >> 2, g = r & 3;
  const int src = g*HIDN + j;
  for (int e4 = lane32; e4 < 128; e4 += 32){
    const int e = e4*4;
    *reinterpret_cast<uint2*>(Whc + (size_t)r*512 + e) =
        *reinterpret_cast<const uint2*>(Whh + (size_t)src*HIDN + e);
  }
  for (int e4 = lane32; e4 < 64; e4 += 32){
    const int e = e4*4;
    *reinterpret_cast<uint2*>(Wemb + (size_t)r*256 + e) =
        *reinterpret_cast<const uint2*>(Wih + (size_t)src*768 + e);
  }
  for (int e4 = lane32; e4 < 128; e4 += 32){
    const int e = e4*4;
    *reinterpret_cast<uint2*>(Wctx + (size_t)r*512 + e) =
        *reinterpret_cast<const uint2*>(Wih + (size_t)src*768 + 256 + e);
  }
  if (lane32 == 0) biasCatB[r] = __float2bfloat16(b2f(bih[src]) + b2f(bhh[src]));
}

// ---------- embAll[b*60+t][256] = table[captions[b*60+t]] ----------
__global__ void __launch_bounds__(64) k_embgather(const int* __restrict__ captions,
      const bf16* __restrict__ table, bf16* __restrict__ embAll){
  const int row = blockIdx.x;
  const int tok = captions[row];
  const uint2* s = reinterpret_cast<const uint2*>(table + (size_t)tok*EMBN);
  uint2* d = reinterpret_cast<uint2*>(embAll + (size_t)row*EMBN);
  d[threadIdx.x] = s[threadIdx.x];
}

// ---------- g = mean_p cnn ; h0, c0 (published coherently) ----------
__global__ void __launch_bounds__(256) k_init(const bf16* __restrict__ cnn,
      const bf16* __restrict__ Wh, const bf16* __restrict__ bh,
      const bf16* __restrict__ Wc, const bf16* __restrict__ bc,
      float* __restrict__ h, float* __restrict__ c){
  __shared__ float gl[FEATC];
  int b = blockIdx.x, tid = threadIdx.x;
  for (int cc = tid; cc < FEATC; cc += 256){
    const bf16* src = cnn + ((size_t)b*FEATC + cc)*PPN;
    const uint2* sp = reinterpret_cast<const uint2*>(src);
    float acc = 0.f;
    for (int q=0;q<PPN/4;q++){
      uint2 u = sp[q];
      acc += __uint_as_float(u.x<<16) + __uint_as_float(u.x&0xffff0000u)
           + __uint_as_float(u.y<<16) + __uint_as_float(u.y&0xffff0000u);
    }
    gl[cc] = acc * (1.0f/196.0f);
  }
  __syncthreads();
  for (int i = tid; i < HIDN; i += 256){
    const uint4* wr1 = reinterpret_cast<const uint4*>(Wh + (size_t)i*FEATC);
    const uint4* wr2 = reinterpret_cast<const uint4*>(Wc + (size_t)i*FEATC);
    float a1 = 0.f, a2 = 0.f;
    #pragma unroll 4
    for (int k8=0; k8<FEATC/8; k8++){
      float w1[8], w2[8];
      unpack8(wr1[k8], w1); unpack8(wr2[k8], w2);
      const float* gp = &gl[k8*8];
      #pragma unroll
      for (int j=0;j<8;j++){ a1 = fmaf(w1[j], gp[j], a1); a2 = fmaf(w2[j], gp[j], a2); }
    }
    astore(&h[b*HIDN+i], a1 + b2f(bh[i]));
    astore(&c[b*HIDN+i], a2 + b2f(bc[i]));
  }
}

// ---------- initial hk partials from h0 ----------
__global__ void __launch_bounds__(512) k_hk0(const bf16* __restrict__ WkT,
      const float* __restrict__ h, float* __restrict__ part){
  __shared__ float hl[64];
  const int tid = threadIdx.x;
  const int k = blockIdx.x & 7, b = blockIdx.x >> 3;
  if (tid < 64) hl[tid] = aload(&h[b*HIDN + k*64 + tid]);
  __syncthreads();
  const bf16* wp = WkT + (size_t)(k*64)*AFFN + tid;
  float acc = 0.f;
  #pragma unroll 8
  for (int j=0; j<64; j++) acc = fmaf(b2f(wp[(size_t)j*AFFN]), hl[j], acc);
  astore(&part[((size_t)(b*8 + k))*AFFN + tid], acc);
}

// ---------- generic MFMA GEMM: C[M][N] = A[M][K] @ Bw[N][K]^T (+bias) ----------
template<int OUTMODE, bool BIAS, bool NT>
__global__ void __launch_bounds__(256) gemm_bt(const bf16* __restrict__ A, const bf16* __restrict__ Bw,
        const bf16* __restrict__ bias, void* __restrict__ Cout, int M, int N, int K,
        const int* __restrict__ flag){
  __shared__ __align__(16) bf16 As[64][40];
  __shared__ __align__(16) bf16 Bs[64][40];
  int tid = threadIdx.x;
  int m0 = blockIdx.y*64, n0 = blockIdx.x*64;
  int lr = tid >> 2;
  int lk = (tid & 3)*8;
  int wave = tid >> 6, lane = tid & 63;
  int ml = lane & 15, kg = lane >> 4;
  f32x4 acc0 = {0.f,0.f,0.f,0.f}, acc1 = acc0, acc2 = acc0, acc3 = acc0;
  for (int k0=0; k0<K; k0+=32){
    __syncthreads();
    {
      uint4 av = *reinterpret_cast<const uint4*>(A + (size_t)(m0+lr)*K + k0 + lk);
      *reinterpret_cast<uint4*>(&As[lr][lk]) = av;
      uint4 bv = make_uint4(0u,0u,0u,0u);
      int bn = n0 + lr;
      if (bn < N) bv = *reinterpret_cast<const uint4*>(Bw + (size_t)bn*K + k0 + lk);
      *reinterpret_cast<uint4*>(&Bs[lr][lk]) = bv;
    }
    __syncthreads();
    short8 af = *reinterpret_cast<const short8*>(&As[wave*16 + ml][kg*8]);
    short8 b0 = *reinterpret_cast<const short8*>(&Bs[ 0 + ml][kg*8]);
    short8 b1 = *reinterpret_cast<const short8*>(&Bs[16 + ml][kg*8]);
    short8 b2 = *reinterpret_cast<const short8*>(&Bs[32 + ml][kg*8]);
    short8 b3 = *reinterpret_cast<const short8*>(&Bs[48 + ml][kg*8]);
    acc0 = __builtin_amdgcn_mfma_f32_16x16x32_bf16(af, b0, acc0, 0,0,0);
    acc1 = __builtin_amdgcn_mfma_f32_16x16x32_bf16(af, b1, acc1, 0,0,0);
    acc2 = __builtin_amdgcn_mfma_f32_16x16x32_bf16(af, b2, acc2, 0,0,0);
    acc3 = __builtin_amdgcn_mfma_f32_16x16x32_bf16(af, b3, acc3, 0,0,0);
  }
  bool of32;
  if (OUTMODE == 0) of32 = true;
  else if (OUTMODE == 2) of32 = false;
  else of32 = (flag[0] != 0);
  int mb = m0 + wave*16 + (lane>>4)*4;
  int cl = lane & 15;
  f32x4 av[4] = {acc0, acc1, acc2, acc3};
  #pragma unroll
  for (int j=0;j<4;j++){
    int n = n0 + j*16 + cl;
    if (n < N){
      float bv = BIAS ? b2f(bias[n]) : 0.f;
      #pragma unroll
      for (int rr=0; rr<4; rr++){
        float v = av[j][rr] + bv;
        if (of32){
          float* p = &((float*)Cout)[(size_t)(mb+rr)*N + n];
          if (NT) __builtin_nontemporal_store(v, p); else *p = v;
        } else {
          bf16 hv = __float2bfloat16(v);
          short sv = *reinterpret_cast<short*>(&hv);
          short* p = reinterpret_cast<short*>(&((bf16*)Cout)[(size_t)(mb+rr)*N + n]);
          if (NT) __builtin_nontemporal_store(sv, p); else *p = sv;
        }
      }
    }
  }
}

// ---------- G precompute: G_b[2048][196] = Wctx[2048][512] @ feats_b[196][512]^T ----------
__global__ void __launch_bounds__(256) gemm_gb(const bf16* __restrict__ A, const bf16* __restrict__ BwAll,
        bf16* __restrict__ Gout){
  const bf16* Bw = BwAll + (size_t)blockIdx.z*PPN*FEATC;
  bf16* Cout = Gout + (size_t)blockIdx.z*GROWS*PPN;
  __shared__ __align__(16) bf16 As[64][40];
  __shared__ __align__(16) bf16 Bs[64][40];
  int tid = threadIdx.x;
  int m0 = blockIdx.y*64, n0 = blockIdx.x*64;
  int lr = tid >> 2;
  int lk = (tid & 3)*8;
  int wave = tid >> 6, lane = tid & 63;
  int ml = lane & 15, kg = lane >> 4;
  f32x4 acc0 = {0.f,0.f,0.f,0.f}, acc1 = acc0, acc2 = acc0, acc3 = acc0;
  for (int k0=0; k0<FEATC; k0+=32){
    __syncthreads();
    {
      uint4 av = *reinterpret_cast<const uint4*>(A + (size_t)(m0+lr)*FEATC + k0 + lk);
      *reinterpret_cast<uint4*>(&As[lr][lk]) = av;
      uint4 bv = make_uint4(0u,0u,0u,0u);
      int bn = n0 + lr;
      if (bn < PPN) bv = *reinterpret_cast<const uint4*>(Bw + (size_t)bn*FEATC + k0 + lk);
      *reinterpret_cast<uint4*>(&Bs[lr][lk]) = bv;
    }
    __syncthreads();
    short8 af = *reinterpret_cast<const short8*>(&As[wave*16 + ml][kg*8]);
    short8 b0 = *reinterpret_cast<const short8*>(&Bs[ 0 + ml][kg*8]);
    short8 b1 = *reinterpret_cast<const short8*>(&Bs[16 + ml][kg*8]);
    short8 b2 = *reinterpret_cast<const short8*>(&Bs[32 + ml][kg*8]);
    short8 b3 = *reinterpret_cast<const short8*>(&Bs[48 + ml][kg*8]);
    acc0 = __builtin_amdgcn_mfma_f32_16x16x32_bf16(af, b0, acc0, 0,0,0);
    acc1 = __builtin_amdgcn_mfma_f32_16x16x32_bf16(af, b1, acc1, 0,0,0);
    acc2 = __builtin_amdgcn_mfma_f32_16x16x32_bf16(af, b2, acc2, 0,0,0);
    acc3 = __builtin_amdgcn_mfma_f32_16x16x32_bf16(af, b3, acc3, 0,0,0);
  }
  int mb = m0 + wave*16 + (lane>>4)*4;
  int cl = lane & 15;
  f32x4 av[4] = {acc0, acc1, acc2, acc3};
  #pragma unroll
  for (int j=0;j<4;j++){
    int n = n0 + j*16 + cl;
    if (n < PPN){
      #pragma unroll
      for (int rr=0; rr<4; rr++)
        Cout[(size_t)(mb+rr)*PPN + n] = __float2bfloat16(av[j][rr]);
    }
  }
}

// ---------- barrier wait (flags already signaled separately) ----------
__device__ __forceinline__ void fbar_wait(unsigned* f8, unsigned token){
  const int lane = threadIdx.x & 63;
  unsigned guard = 0;
  for (;;){
    unsigned v = (lane < 8) ? aloadu(&f8[lane]) : token;
    if (__all((int)(v >= token))) break;
    if (++guard > 50000000u) break;
    __builtin_amdgcn_s_sleep(1);
  }
  __syncthreads();
}

// gate partial accumulator
__device__ __forceinline__ void gacc(const bf16* w, const float* x, int len,
                                     float& a0, float& a1, float& a2, float& a3){
  #pragma unroll 4
  for (int e=0; e<len; e+=8){
    float w8[8]; unpack8(*reinterpret_cast<const uint4*>(w+e), w8);
    float4 x0 = *reinterpret_cast<const float4*>(x+e);
    float4 x1 = *reinterpret_cast<const float4*>(x+e+4);
    a0 = fmaf(w8[0],x0.x,a0); a1 = fmaf(w8[1],x0.y,a1);
    a2 = fmaf(w8[2],x0.z,a2); a3 = fmaf(w8[3],x0.w,a3);
    a0 = fmaf(w8[4],x1.x,a0); a1 = fmaf(w8[5],x1.y,a1);
    a2 = fmaf(w8[6],x1.z,a2); a3 = fmaf(w8[7],x1.w,a3);
  }
}

// ---------- persistent recurrence: G + Gemb tricks, 2 overlapped barriers/step ----------
__global__ void __launch_bounds__(512) k_pers(
    const bf16* __restrict__ kvB, const bf16* __restrict__ WkT,
    const bf16* __restrict__ Whc, const bf16* __restrict__ Gglob,
    const bf16* __restrict__ Gemb, const bf16* __restrict__ wa,
    float* __restrict__ hstate, const float* __restrict__ cinit,
    float* __restrict__ part,            // [32][8][512]
    float* __restrict__ zarr,            // [32][8][32]
    bf16* __restrict__ Hb, unsigned* __restrict__ flags)
{
  extern __shared__ __align__(16) char dynsm[];
  bf16* kv_s = reinterpret_cast<bf16*>(dynsm);            // [25][512]
  bf16* G_s  = reinterpret_cast<bf16*>(dynsm + 25600);    // [256][196]
  __shared__ __align__(16) float hs[512];    // h
  __shared__ __align__(16) float hks[512];   // hk sums; reused as part staging
  __shared__ __align__(16) float als[200];
  __shared__ __align__(16) float gs[256];
  __shared__ __align__(16) float zes[32];
  __shared__ __align__(16) float hnew[64];
  __shared__ __align__(8)  bf16 gembs[256];

  const int tid = threadIdx.x;
  const int bid = blockIdx.x;
  const int k = bid & 7, b = bid >> 3;
  unsigned* fl = flags + b*32;
  const int np = (k < 4) ? 25 : 24;
  const int p0 = (k < 4) ? k*25 : 100 + (k-4)*24;
  const int lane = tid & 63, wv = tid >> 6;
  const int r2 = tid >> 1, half = tid & 1;
  const int rowg = k*256 + r2;

  // ---- prologue: stage kv p-slice, G row-slice, gemb(t=0) ----
  {
    const uint4* src = reinterpret_cast<const uint4*>(kvB + ((size_t)(b*PPN + p0))*AFFN);
    uint4* dst = reinterpret_cast<uint4*>(kv_s);
    for (int i = tid; i < np*64; i += 512) dst[i] = src[i];
  }
  {
    const uint2* src = reinterpret_cast<const uint2*>(Gglob + ((size_t)(b*GROWS) + k*256)*PPN);
    uint2* dst = reinterpret_cast<uint2*>(G_s);
    for (int i = tid; i < 12544; i += 512) dst[i] = src[i];
  }
  if (tid < 64)
    *reinterpret_cast<uint2*>(&gembs[tid*4]) =
        *reinterpret_cast<const uint2*>(Gemb + (size_t)(b*TTN + 0)*GROWS + k*256 + tid*4);
  float creg = 0.f;
  if (tid < 64) creg = cinit[b*HIDN + k*64 + tid];
  float wf[8];
  unpack8(*reinterpret_cast<const uint4*>(wa + lane*8), wf);
  __syncthreads();

  for (int t = 0; t < TTN; t++){
    // ---- A0: sum hk partials
    {
      f32x4 pq[8];
      if (tid < 128){
        const float* pp = part + (size_t)b*8*AFFN + tid*4;
        #pragma unroll
        for (int kk=0;kk<8;kk++) pq[kk] = ic_load4(pp + (size_t)kk*AFFN);
      }
      ic_wait();
      if (tid < 128){
        f32x4 s = pq[0];
        #pragma unroll
        for (int kk=1;kk<8;kk++) s += pq[kk];
        *reinterpret_cast<f32x4*>(&hks[tid*4]) = s;
      }
    }
    __syncthreads();

    // ---- z for my p-slice (wave per p), kv from LDS
    {
      float hf[8];
      const float4* hp = reinterpret_cast<const float4*>(&hks[lane*8]);
      float4 t0 = hp[0], t1 = hp[1];
      hf[0]=t0.x; hf[1]=t0.y; hf[2]=t0.z; hf[3]=t0.w;
      hf[4]=t1.x; hf[5]=t1.y; hf[6]=t1.z; hf[7]=t1.w;
      for (int pl = wv; pl < np; pl += 8){
        float kf[8]; unpack8(*reinterpret_cast<const uint4*>(kv_s + pl*512 + lane*8), kf);
        float acc = wf[0]*ftanhf(kf[0]+hf[0]) + wf[1]*ftanhf(kf[1]+hf[1])
                  + wf[2]*ftanhf(kf[2]+hf[2]) + wf[3]*ftanhf(kf[3]+hf[3])
                  + wf[4]*ftanhf(kf[4]+hf[4]) + wf[5]*ftanhf(kf[5]+hf[5])
                  + wf[6]*ftanhf(kf[6]+hf[6]) + wf[7]*ftanhf(kf[7]+hf[7]);
        #pragma unroll
        for (int s=1;s<64;s<<=1) acc += __shfl_xor(acc, s, 64);
        if (lane == 0) zes[pl] = acc;
      }
    }
    __syncthreads();

    // ---- issue z store AND h loads; one drain; signal A
    f32x4 hq;
    if (tid < 8) ic_store4(&zarr[(size_t)(b*8+k)*32 + tid*4],
                           *reinterpret_cast<f32x4*>(&zes[tid*4]));
    if (tid < 128) hq = ic_load4(hstate + (size_t)b*HIDN + tid*4);
    ic_wait();
    __syncthreads();
    if (tid == 0) astoreu(&fl[k], (unsigned)(2*t+1));
    if (tid < 128) *reinterpret_cast<f32x4*>(&hs[tid*4]) = hq;
    __syncthreads();

    // ---- window A: h-part of gates (512 cols) overlaps barrier arrival
    float a0=0.f,a1=0.f,a2=0.f,a3=0.f;
    gacc(Whc + (size_t)rowg*512 + half*256, hs + half*256, 256, a0,a1,a2,a3);

    fbar_wait(fl, (unsigned)(2*t+1));   // -------- barrier A --------

    // ---- gather z, local full softmax
    f32x4 zq;
    if (tid < 64) zq = ic_load4(&zarr[(size_t)b*256 + tid*4]);
    ic_wait();
    if (tid < 64){
      const int kk2 = tid >> 3, i0 = (tid & 7)*4;
      const int npk = (kk2 < 4) ? 25 : 24;
      const int p0k = (kk2 < 4) ? kk2*25 : 100 + (kk2-4)*24;
      #pragma unroll
      for (int jj=0;jj<4;jj++) if (i0+jj < npk) als[p0k+i0+jj] = zq[jj];
    }
    __syncthreads();
    if (wv == 0){
      float m = -1e30f;
      for (int i=lane;i<PPN;i+=64) m = fmaxf(m, als[i]);
      #pragma unroll
      for (int s=1;s<64;s<<=1) m = fmaxf(m, __shfl_xor(m, s, 64));
      float ssum = 0.f;
      for (int i=lane;i<PPN;i+=64){
        float e = fexp2((als[i]-m)*1.4426950408889634f);
        als[i] = e; ssum += e;
      }
      #pragma unroll
      for (int s=1;s<64;s<<=1) ssum += __shfl_xor(ssum, s, 64);
      float inv = 1.0f/ssum;
      for (int i=lane;i<PPN;i+=64) als[i] *= inv;
    }
    __syncthreads();

    // ---- ctx via G + fold with Gemb (bias folded in Gemb)
    float ga = 0.f;
    {
      const uint32_t* gr = reinterpret_cast<const uint32_t*>(G_s + r2*PPN + half*98);
      const float* ap = als + half*98;
      #pragma unroll 7
      for (int i=0;i<49;i++){
        uint32_t u = gr[i];
        ga = fmaf(__uint_as_float(u << 16),          ap[2*i],   ga);
        ga = fmaf(__uint_as_float(u & 0xffff0000u),  ap[2*i+1], ga);
      }
    }
    {
      float acc = (a0+a1)+(a2+a3) + ga;
      acc += __shfl_xor(acc, 1, 64);
      if (half == 0) gs[r2] = acc + b2f(gembs[r2]);
    }
    __syncthreads();

    // ---- cell update (c in registers)
    if (tid < 64){
      float gi = gs[tid*4+0], gf = gs[tid*4+1], gg = gs[tid*4+2], go = gs[tid*4+3];
      float cn = fsig(gf)*creg + fsig(gi)*ftanhf(gg);
      float hn = fsig(go)*ftanhf(cn);
      creg = cn;
      hnew[tid] = hn;
    }
    __syncthreads();

    // ---- h store + next-step hk partial
    if (tid < 16) ic_store4(&hstate[(size_t)b*HIDN + k*64 + tid*4],
                            *reinterpret_cast<f32x4*>(&hnew[tid*4]));
    {
      const bf16* wp = WkT + (size_t)(k*64)*AFFN + tid;
      float acc = 0.f;
      #pragma unroll 8
      for (int j=0;j<64;j++) acc = fmaf(b2f(wp[(size_t)j*AFFN]), hnew[j], acc);
      hks[tid] = acc;
    }
    __syncthreads();
    if (tid < 128) ic_store4(&part[((size_t)(b*8+k))*AFFN + tid*4],
                             *reinterpret_cast<f32x4*>(&hks[tid*4]));

    // ---- signal B; window B: Hb store + gemb(t+1) prefetch
    ic_wait();
    __syncthreads();
    if (tid == 0) astoreu(&fl[k], (unsigned)(2*t+2));
    if (tid < 64) Hb[((size_t)b*TTN + t)*HIDN + k*64 + tid] = __float2bfloat16(hnew[tid]);
    {
      const int tn = (t+1 < TTN) ? t+1 : t;
      if (tid < 64)
        *reinterpret_cast<uint2*>(&gembs[tid*4]) =
            *reinterpret_cast<const uint2*>(Gemb + (size_t)(b*TTN + tn)*GROWS + k*256 + tid*4);
    }
    fbar_wait(fl, (unsigned)(2*t+2));   // -------- barrier B --------
  }
}

extern "C" void kernel_launch(void* const* d_in, const int* in_sizes, int n_in,
                              void* d_out, int out_size, void* d_ws, size_t ws_size,
                              hipStream_t stream) {
  const int* captions = (const int*)d_in[1];
  char* ws = (char*)d_ws;

  // ---- workspace layout (bytes) ----
  bf16*  feats  = (bf16*) (ws + 0);           // [6272][512] bf16
  bf16*  kvB    = (bf16*) (ws + 6422528);
  float* hstate = (float*)(ws + 12845056);    // [32][512]
  float* cstate = (float*)(ws + 12910592);
  float* part   = (float*)(ws + 12976128);    // [32][8][512]
  float* zarr   = (float*)(ws + 13500416);    // [32][8][32]
  unsigned* flags=(unsigned*)(ws + 13533184);
  bf16*  Hb     = (bf16*) (ws + 13537280);    // [32][60][512]
  bf16*  cnnB   = (bf16*) (ws + 15503360);    // dead after transpose+init; aliased below
  bf16*  WhcB   = (bf16*) (ws + 15503360);    // [2048][512]
  bf16*  WembB  = (bf16*) (ws + 17600512 + 2097152 - 2097152 + 2097152); // = 17600512+2097152
  bf16*  WctxB  = (bf16*) (ws + 17600512);    // [2048][512]
  bf16*  tableB = (bf16*) (ws + 21925888);
  bf16*  WkB    = (bf16*) (ws + 27045888);
  bf16*  WkTB   = (bf16*) (ws + 27570176);
  bf16*  WvB    = (bf16*) (ws + 28094464);
  bf16*  WhB    = (bf16*) (ws + 28618752);
  bf16*  WcB    = (bf16*) (ws + 29143040);
  bf16*  WihB   = (bf16*) (ws + 29667328);
  bf16*  WhhB   = (bf16*) (ws + 32813056);
  bf16*  waB    = (bf16*) (ws + 34910208);
  bf16*  bhB    = (bf16*) (ws + 34911232);
  bf16*  bcB    = (bf16*) (ws + 34912256);
  bf16*  bihB   = (bf16*) (ws + 34913280);
  bf16*  bhhB   = (bf16*) (ws + 34917376);
  bf16*  bfcB   = (bf16*) (ws + 34921472);
  bf16*  biasCatB=(bf16*) (ws + 34941472);
  int*   flag   = (int*)  (ws + 34945568);
  bf16*  embAll = (bf16*) (ws + 34945600);    // [1920][256]
  bf16*  WfcB   = (bf16*) (ws + 35928640);    // [10000][512] — converted AFTER k_pers
  bf16*  Gemb   = (bf16*) (ws + 35928640);    // [1920][2048] — aliases WfcB during k_pers
  if (ws_size < 46168656ull) return;
  WembB = (bf16*)(ws + 19697664);             // [2048][256] (aliases cnnB tail)

  bf16* Gglob = (bf16*)d_out;                 // G scratch in d_out (25.7MB)

  // 1) dtype probe + flag reset
  k_probe<<<1, 256, 0, stream>>>((const uint32_t*)d_in[5], flag, flags);

  // 2) batched canonicalize (all except Wfc)
  CvtJobs J;
  const void* srcs[14] = { d_in[0], d_in[2], d_in[3], d_in[4], d_in[5], d_in[6], d_in[7],
                           d_in[8], d_in[9], d_in[10], d_in[11], d_in[12], d_in[13], d_in[15] };
  void* dsts[14] = { cnnB, WkB, WvB, waB, tableB, WhB, bhB, WcB, bcB, WihB, WhhB, bihB, bhhB, bfcB };
  const int ns[14] = { 3211264, 262144, 262144, 512, 2560000, 262144, 512,
                       262144, 512, 1572864, 1048576, 2048, 2048, 10000 };
  for (int i=0;i<14;i++){ J.src[i]=srcs[i]; J.dst[i]=dsts[i]; J.nq[i]=ns[i]/4; }
  k_cvtall<<<dim3(256,14), 256, 0, stream>>>(J, flag);

  // 3) precompute (cnnB consumers BEFORE k_wcat3 overwrites the region)
  k_transpose<<<dim3(16,7,32), 256, 0, stream>>>(cnnB, feats);
  k_init<<<32, 256, 0, stream>>>(cnnB, WhB, bhB, WcB, bcB, hstate, cstate);
  k_wkt<<<dim3(16,16), 256, 0, stream>>>(WkB, WkTB);
  k_wcat3<<<256, 256, 0, stream>>>(WihB, WhhB, bihB, bhhB, WhcB, WembB, WctxB, biasCatB);
  k_hk0<<<256, 512, 0, stream>>>(WkTB, hstate, part);
  gemm_bt<2,false,false><<<dim3(8,98), 256, 0, stream>>>(feats, WvB, (const bf16*)nullptr,
                                                   (void*)kvB, 6272, 512, 512, (const int*)nullptr);
  gemm_gb<<<dim3(4,32,32), 256, 0, stream>>>(WctxB, feats, Gglob);
  k_embgather<<<1920, 64, 0, stream>>>(captions, tableB, embAll);
  gemm_bt<2,true,false><<<dim3(32,30), 256, 0, stream>>>(embAll, WembB, biasCatB,
                                                   (void*)Gemb, 1920, 2048, 256, (const int*)nullptr);

  // 4) recurrence: ONE persistent kernel (dyn LDS: kv 25KB + G 100KB)
  k_pers<<<256, 512, 125952, stream>>>(kvB, WkTB, WhcB, Gglob, Gemb, waB,
                                       hstate, cstate, part, zarr, Hb, flags);

  // 5) convert Wfc now (its region held Gemb during k_pers), then logits
  k_cvt<<<1024, 256, 0, stream>>>(d_in[14], WfcB, 1280000, flag);
  gemm_bt<1,true,true><<<dim3(157,30), 256, 0, stream>>>(Hb, WfcB, bfcB, d_out,
                                                    1920, 10000, 512, flag);
}